// Round 8
// baseline (252.995 us; speedup 1.0000x reference)
//
#include <hip/hip_runtime.h>
#include <cstdint>
#include <cstddef>

#define BB 512
#define NEn 100000
#define NRr 400
#define AA 256
#define ENTd 200
#define RELd 200
#define HISTd 400
#define ADIMd 400

__device__ __forceinline__ float dot4(const float4 a, const float4 b) {
  return a.x * b.x + a.y * b.y + a.z * b.z + a.w * b.w;
}
__device__ __forceinline__ float wave_rmax(float v) {
#pragma unroll
  for (int off = 32; off > 0; off >>= 1) v = fmaxf(v, __shfl_xor(v, off));
  return v;
}
__device__ __forceinline__ float wave_rsum(float v) {
#pragma unroll
  for (int off = 32; off > 0; off >>= 1) v += __shfl_xor(v, off);
  return v;
}

// ---------------------------------------------------------------------------
// prep1: RK, P, W6bb, ab + tiled transposes relT/WaT/W1T/W2T
// ---------------------------------------------------------------------------
__global__ __launch_bounds__(256) void prep1_kernel(
    const float* __restrict__ rel_emb, const float* __restrict__ W4,
    const float* __restrict__ b4, const float* __restrict__ W5,
    const float* __restrict__ b5, const float* __restrict__ W6,
    const float* __restrict__ Watt, const float* __restrict__ W1,
    const float* __restrict__ W2, float* __restrict__ RK,
    float* __restrict__ P, float* __restrict__ W6bb, float* __restrict__ ab,
    float* __restrict__ relT, float* __restrict__ WaT,
    float* __restrict__ W1T, float* __restrict__ W2T) {
  int t = threadIdx.x;
  int blk = blockIdx.x;
  if (blk == 0) {
    __shared__ float rs[RELd];
    if (t < RELd) {
      float s = 0.f;
      for (int r = 0; r < NRr; r += 4) {
        s += rel_emb[(size_t)r * RELd + t] + rel_emb[(size_t)(r + 1) * RELd + t] +
             rel_emb[(size_t)(r + 2) * RELd + t] + rel_emb[(size_t)(r + 3) * RELd + t];
      }
      rs[t] = s;
    }
    __syncthreads();
    if (t < RELd) {
      float acc = b5[t];
      const float4* w = (const float4*)(W5 + (size_t)t * 400);
      const float4* rv = (const float4*)rs;
      for (int k = 0; k < 50; ++k) acc += dot4(w[k], rv[k]);
      ab[t] = acc;
    }
  } else if (blk <= 50) {
    int r0 = (blk - 1) * 8;
    __shared__ float re[8][RELd];
    for (int i = t; i < 8 * RELd; i += 256)
      re[i / RELd][i % RELd] = rel_emb[(size_t)(r0 + i / RELd) * RELd + i % RELd];
    __syncthreads();
    if (t < RELd) {
      float bv = b4[t];
      float acc[8];
#pragma unroll
      for (int s = 0; s < 8; ++s) acc[s] = bv;
      const float4* w = (const float4*)(W4 + (size_t)t * RELd);
      for (int k = 0; k < 50; ++k) {
        float4 wv = w[k];
#pragma unroll
        for (int s = 0; s < 8; ++s) acc[s] += dot4(wv, ((const float4*)re[s])[k]);
      }
#pragma unroll
      for (int s = 0; s < 8; ++s) RK[(size_t)(r0 + s) * RELd + t] = acc[s];
    }
  } else if (blk <= 75) {
    int i0 = (blk - 51) * 8;
    __shared__ float w6s[8][200];
    for (int i = t; i < 8 * 200; i += 256)
      w6s[i / 200][i % 200] = W6[(size_t)(i0 + i / 200) * 400 + i % 200];
    __syncthreads();
    if (t < 200) {
      int k = t;
      float acc[8] = {0, 0, 0, 0, 0, 0, 0, 0};
      for (int j = 0; j < 200; j += 4) {
        float r0v = W5[(size_t)j * 400 + 200 + k];
        float r1v = W5[(size_t)(j + 1) * 400 + 200 + k];
        float r2v = W5[(size_t)(j + 2) * 400 + 200 + k];
        float r3v = W5[(size_t)(j + 3) * 400 + 200 + k];
#pragma unroll
        for (int s = 0; s < 8; ++s)
          acc[s] += w6s[s][j] * r0v + w6s[s][j + 1] * r1v + w6s[s][j + 2] * r2v +
                    w6s[s][j + 3] * r3v;
      }
#pragma unroll
      for (int s = 0; s < 8; ++s) P[(size_t)(i0 + s) * 200 + k] = 400.f * acc[s];
    }
  } else if (blk <= 100) {
    int u0 = (blk - 76) * 8;
    __shared__ float wbs[8][200];
    for (int i = t; i < 8 * 200; i += 256)
      wbs[i / 200][i % 200] = Watt[(size_t)(u0 + i / 200) * 600 + 400 + i % 200];
    __syncthreads();
    if (t < 200) {
      int j = t;
      float acc[8] = {0, 0, 0, 0, 0, 0, 0, 0};
      for (int i = 0; i < 200; i += 4) {
        float r0v = W6[(size_t)i * 400 + 200 + j];
        float r1v = W6[(size_t)(i + 1) * 400 + 200 + j];
        float r2v = W6[(size_t)(i + 2) * 400 + 200 + j];
        float r3v = W6[(size_t)(i + 3) * 400 + 200 + j];
#pragma unroll
        for (int s = 0; s < 8; ++s)
          acc[s] += wbs[s][i] * r0v + wbs[s][i + 1] * r1v + wbs[s][i + 2] * r2v +
                    wbs[s][i + 3] * r3v;
      }
#pragma unroll
      for (int s = 0; s < 8; ++s) W6bb[(size_t)(u0 + s) * 200 + j] = acc[s];
    }
  } else {
    __shared__ float tlds[64][65];
    int tb = blk - 101;
    const float* src;
    float* dst;
    int M, N, LD, ti, tj;
    if (tb < 28) {
      src = rel_emb; dst = relT; M = 400; N = 200; LD = 200;
      ti = tb / 4; tj = tb % 4;
    } else if (tb < 56) {
      tb -= 28;
      src = Watt; dst = WaT; M = 200; N = 400; LD = 600;
      ti = tb / 7; tj = tb % 7;
    } else if (tb < 147) {
      tb -= 56;
      src = W1; dst = W1T; M = 400; N = 800; LD = 800;
      ti = tb / 13; tj = tb % 13;
    } else {
      tb -= 147;
      src = W2; dst = W2T; M = 400; N = 400; LD = 400;
      ti = tb / 7; tj = tb % 7;
    }
    int i0 = ti * 64, j0 = tj * 64;
    for (int idx = t; idx < 4096; idx += 256) {
      int r = idx >> 6, c = idx & 63;
      int i = i0 + r, j = j0 + c;
      if (i < M && j < N) tlds[r][c] = src[(size_t)i * LD + j];
    }
    __syncthreads();
    for (int idx = t; idx < 4096; idx += 256) {
      int r = idx >> 6, c = idx & 63;
      int j = j0 + r, i = i0 + c;
      if (i < M && j < N) dst[(size_t)j * M + i] = tlds[c][r];
    }
  }
}

// ---------------------------------------------------------------------------
// prep2: S_T, cvec, Q_T, REatt, v1 (unchanged)
// ---------------------------------------------------------------------------
__global__ __launch_bounds__(256) void prep2_kernel(
    const float* __restrict__ rel_emb, const float* __restrict__ W3,
    const float* __restrict__ b3, const float* __restrict__ W6,
    const float* __restrict__ Watt, const float* __restrict__ batt,
    const float* __restrict__ b6, const float* __restrict__ RK,
    const float* __restrict__ P, const float* __restrict__ W6bb,
    const float* __restrict__ ab, float* __restrict__ S_T,
    float* __restrict__ cvec, float* __restrict__ Q_T,
    float* __restrict__ REatt, float* __restrict__ v1) {
  int t = threadIdx.x;
  int blk = blockIdx.x;
  if (blk < 50) {
    int r0 = blk * 8;
    __shared__ float rks[8][200];
    __shared__ float b3s[200];
    for (int i = t; i < 8 * 200; i += 256)
      rks[i / 200][i % 200] = RK[(size_t)(r0 + i / 200) * 200 + i % 200];
    if (t < 200) b3s[t] = b3[t];
    __syncthreads();
    if (t < 200) {
      int i = t;
      float acc[8] = {0, 0, 0, 0, 0, 0, 0, 0};
      for (int j = 0; j < 200; j += 4) {
        float w0 = W3[(size_t)j * 200 + i];
        float w1 = W3[(size_t)(j + 1) * 200 + i];
        float w2 = W3[(size_t)(j + 2) * 200 + i];
        float w3v = W3[(size_t)(j + 3) * 200 + i];
#pragma unroll
        for (int s = 0; s < 8; ++s)
          acc[s] += w0 * rks[s][j] + w1 * rks[s][j + 1] + w2 * rks[s][j + 2] +
                    w3v * rks[s][j + 3];
      }
      float4 s0 = make_float4(acc[0], acc[1], acc[2], acc[3]);
      float4 s1 = make_float4(acc[4], acc[5], acc[6], acc[7]);
      *(float4*)(S_T + (size_t)i * 400 + r0) = s0;
      *(float4*)(S_T + (size_t)i * 400 + r0 + 4) = s1;
    }
    {
      int w = t >> 6, lane = t & 63;
      float p0 = 0.f, p1 = 0.f;
      for (int j = lane; j < 200; j += 64) {
        p0 += b3s[j] * rks[w][j];
        p1 += b3s[j] * rks[w + 4][j];
      }
      p0 = wave_rsum(p0);
      p1 = wave_rsum(p1);
      if (lane == 0) {
        cvec[r0 + w] = p0;
        cvec[r0 + w + 4] = p1;
      }
    }
  } else if (blk < 75) {
    int u0 = (blk - 50) * 8;
    __shared__ float wbs[8][200];
    for (int i = t; i < 8 * 200; i += 256)
      wbs[i / 200][i % 200] = Watt[(size_t)(u0 + i / 200) * 600 + 400 + i % 200];
    __syncthreads();
    if (t < 200) {
      int k = t;
      float acc[8] = {0, 0, 0, 0, 0, 0, 0, 0};
      for (int i = 0; i < 200; i += 4) {
        float r0v = P[(size_t)i * 200 + k];
        float r1v = P[(size_t)(i + 1) * 200 + k];
        float r2v = P[(size_t)(i + 2) * 200 + k];
        float r3v = P[(size_t)(i + 3) * 200 + k];
#pragma unroll
        for (int s = 0; s < 8; ++s)
          acc[s] += wbs[s][i] * r0v + wbs[s][i + 1] * r1v + wbs[s][i + 2] * r2v +
                    wbs[s][i + 3] * r3v;
      }
      float4 s0 = make_float4(acc[0], acc[1], acc[2], acc[3]);
      float4 s1 = make_float4(acc[4], acc[5], acc[6], acc[7]);
      *(float4*)(Q_T + (size_t)k * 200 + u0) = s0;
      *(float4*)(Q_T + (size_t)k * 200 + u0 + 4) = s1;
    }
  } else if (blk < 125) {
    int r0 = (blk - 75) * 8;
    __shared__ float rels[8][200];
    for (int i = t; i < 8 * 200; i += 256)
      rels[i / 200][i % 200] = rel_emb[(size_t)(r0 + i / 200) * 200 + i % 200];
    __syncthreads();
    if (t < 200) {
      float acc[8] = {0, 0, 0, 0, 0, 0, 0, 0};
      const float4* w = (const float4*)(W6bb + (size_t)t * 200);
      for (int k = 0; k < 50; ++k) {
        float4 wv = w[k];
#pragma unroll
        for (int s = 0; s < 8; ++s) acc[s] += dot4(wv, ((const float4*)rels[s])[k]);
      }
#pragma unroll
      for (int s = 0; s < 8; ++s) REatt[(size_t)(r0 + s) * 200 + t] = acc[s];
    }
  } else {
    __shared__ float abs_[200];
    __shared__ float us[200];
    if (t < 200) abs_[t] = ab[t];
    __syncthreads();
    if (t < 200) {
      float u = b6[t];
      const float4* w = (const float4*)(W6 + (size_t)t * 400);
      const float4* rv = (const float4*)abs_;
      for (int k = 0; k < 50; ++k) u += dot4(w[k], rv[k]);
      us[t] = u;
    }
    __syncthreads();
    if (t < 200) {
      float v = batt[t];
      const float4* w = (const float4*)(Watt + (size_t)t * 600 + 400);
      const float4* rv = (const float4*)us;
      for (int k = 0; k < 50; ++k) v += dot4(w[k], rv[k]);
      v1[t] = v;
    }
  }
}

// ---------------------------------------------------------------------------
// x1: X = relu(W1T^T . cat(E,H,Q) + b1)  R=8 rows/block, 64 blocks
// ---------------------------------------------------------------------------
__global__ __launch_bounds__(512) void x1_kernel(
    const float* __restrict__ ent_emb, const float* __restrict__ rel_emb,
    const float* __restrict__ H, const int* __restrict__ e_idx,
    const int* __restrict__ q_idx, const float* __restrict__ W1T,
    const float* __restrict__ b1, float* __restrict__ X) {
  int b0 = blockIdx.x * 8;
  int t = threadIdx.x;
  __shared__ float cv[8][800];
  for (int i = t; i < 8 * 800; i += 512) {
    int s = i / 800, k = i % 800;
    float v;
    if (k < ENTd)
      v = ent_emb[(size_t)e_idx[b0 + s] * ENTd + k];
    else if (k < ENTd + HISTd)
      v = H[(size_t)(b0 + s) * HISTd + (k - ENTd)];
    else
      v = rel_emb[(size_t)q_idx[b0 + s] * RELd + (k - ENTd - HISTd)];
    cv[s][k] = v;
  }
  __syncthreads();
  if (t < 400) {
    int j = t;
    float bv = b1[j];
    float acc[8];
#pragma unroll
    for (int s = 0; s < 8; ++s) acc[s] = bv;
    const float* wp = W1T + j;
#pragma unroll 4
    for (int k = 0; k < 800; ++k) {
      float w0 = wp[(size_t)k * 400];
#pragma unroll
      for (int s = 0; s < 8; ++s) acc[s] += w0 * cv[s][k];
    }
#pragma unroll
    for (int s = 0; s < 8; ++s)
      X[(size_t)(b0 + s) * ADIMd + j] = fmaxf(acc[s], 0.f);
  }
}

// ---------------------------------------------------------------------------
// x2rx: X2 = W2T^T . X + b2 ; RX[b][r] = rel_emb[r] . X2[b][:200]
// R=8 rows/block, 64 blocks
// ---------------------------------------------------------------------------
__global__ __launch_bounds__(512) void x2rx_kernel(
    const float* __restrict__ X, const float* __restrict__ W2T,
    const float* __restrict__ b2, const float* __restrict__ relT,
    float* __restrict__ X2, float* __restrict__ RX) {
  int b0 = blockIdx.x * 8;
  int t = threadIdx.x;
  __shared__ float cv[8][400];
  __shared__ float x2lo[8][200];
  for (int i = t; i < 8 * 400; i += 512) cv[i / 400][i % 400] = X[(size_t)b0 * 400 + i];
  __syncthreads();
  if (t < 400) {
    int j = t;
    float bv = b2[j];
    float acc[8];
#pragma unroll
    for (int s = 0; s < 8; ++s) acc[s] = bv;
    const float* wp = W2T + j;
#pragma unroll 4
    for (int k = 0; k < 400; ++k) {
      float w0 = wp[(size_t)k * 400];
#pragma unroll
      for (int s = 0; s < 8; ++s) acc[s] += w0 * cv[s][k];
    }
#pragma unroll
    for (int s = 0; s < 8; ++s) X2[(size_t)(b0 + s) * ADIMd + j] = acc[s];
    if (j < 200) {
#pragma unroll
      for (int s = 0; s < 8; ++s) x2lo[s][j] = acc[s];
    }
  }
  __syncthreads();
  if (t < 400) {
    int r = t;
    const float* rp = relT + r;
    float acc[8] = {0, 0, 0, 0, 0, 0, 0, 0};
#pragma unroll 4
    for (int k = 0; k < 200; ++k) {
      float w0 = rp[(size_t)k * 400];
#pragma unroll
      for (int s = 0; s < 8; ++s) acc[s] += w0 * x2lo[s][k];
    }
#pragma unroll
    for (int s = 0; s < 8; ++s) RX[(size_t)(b0 + s) * NRr + r] = acc[s];
  }
}

// ---------------------------------------------------------------------------
// fused_mid: EIGHT rows/block, 64 blocks x 512 threads; wave-local softmax.
// ---------------------------------------------------------------------------
__global__ __launch_bounds__(512) void fused_mid_kernel(
    const float* __restrict__ ent_emb, const int* __restrict__ pred_id,
    const float* __restrict__ X2, const float* __restrict__ S_T,
    const float* __restrict__ cvec, const float* __restrict__ Q_T,
    const float* __restrict__ REatt, const float* __restrict__ relT,
    const float* __restrict__ WaT, const float* __restrict__ v1c,
    float* __restrict__ out_ratt) {
  int b0 = blockIdx.x * 8;
  int t = threadIdx.x;
  int w = t >> 6, lane = t & 63;
  __shared__ float pes[8][200];
  __shared__ float x2s[8][400];
  __shared__ float pp[8][400];
  __shared__ float av[8][200];
  __shared__ float attp[2][8][200];
  for (int i = t; i < 1600; i += 512)
    pes[i / 200][i % 200] = ent_emb[(size_t)pred_id[b0 + i / 200] * ENTd + i % 200];
  for (int i = t; i < 3200; i += 512)
    x2s[i / 400][i % 400] = X2[(size_t)b0 * 400 + i];
  __syncthreads();
  // --- la: thread r = t (coalesced S_T[k][r]); 8 FMAs per load ---
  if (t < 400) {
    float c = cvec[t];
    float acc[8];
#pragma unroll
    for (int s = 0; s < 8; ++s) acc[s] = c;
    const float* sp = S_T + t;
#pragma unroll 4
    for (int k = 0; k < 200; ++k) {
      float w0 = sp[(size_t)k * 400];
#pragma unroll
      for (int s = 0; s < 8; ++s) acc[s] += w0 * pes[s][k];
    }
#pragma unroll
    for (int s = 0; s < 8; ++s) pp[s][t] = acc[s];
  }
  __syncthreads();
  // --- wave-local softmax: wave w owns row w ---
  {
    float m = -INFINITY;
    for (int r = lane; r < 400; r += 64) m = fmaxf(m, pp[w][r]);
    m = wave_rmax(m);
    float sum = 0.f;
    for (int r = lane; r < 400; r += 64) {
      float e = expf(pp[w][r] - m);
      pp[w][r] = e;
      sum += e;
    }
    sum = wave_rsum(sum);
    float inv = 1.f / sum;
    for (int r = lane; r < 400; r += 64) pp[w][r] *= inv;
  }
  __syncthreads();
  // --- attv: j = t%200, h = t/200 (k-halves); 8 FMAs per load ---
  if (t < 400) {
    int j = t % 200, h = t / 200;
    float acc[8];
    if (h == 0) {
      float v = v1c[j];
#pragma unroll
      for (int s = 0; s < 8; ++s) acc[s] = v;
    } else {
#pragma unroll
      for (int s = 0; s < 8; ++s) acc[s] = 0.f;
    }
    {
      const float* wp = WaT + (size_t)(h * 200) * 200 + j;
      int kb = h * 200;
#pragma unroll 4
      for (int k = 0; k < 200; ++k) {
        float w0 = wp[(size_t)k * 200];
#pragma unroll
        for (int s = 0; s < 8; ++s) acc[s] += w0 * x2s[s][kb + k];
      }
    }
    {
      const float* qp = Q_T + (size_t)(h * 100) * 200 + j;
      int kb = h * 100;
#pragma unroll 4
      for (int k = 0; k < 100; ++k) {
        float w0 = qp[(size_t)k * 200];
#pragma unroll
        for (int s = 0; s < 8; ++s) acc[s] += w0 * pes[s][kb + k];
      }
    }
    {
      const float* rp = REatt + (size_t)(h * 200) * 200 + j;
      int rb = h * 200;
#pragma unroll 4
      for (int r = 0; r < 200; ++r) {
        float w0 = rp[(size_t)r * 200];
#pragma unroll
        for (int s = 0; s < 8; ++s) acc[s] += w0 * pp[s][rb + r];
      }
    }
#pragma unroll
    for (int s = 0; s < 8; ++s) attp[h][s][j] = acc[s];
  }
  __syncthreads();
  for (int i = t; i < 1600; i += 512) {
    int s = i / 200, j = i % 200;
    av[s][j] = attp[0][s][j] + attp[1][s][j];
  }
  __syncthreads();
  // --- logits: thread r = t (coalesced relT[k][r]) ---
  if (t < 400) {
    const float* rp = relT + t;
    float acc[8] = {0, 0, 0, 0, 0, 0, 0, 0};
#pragma unroll 4
    for (int k = 0; k < 200; ++k) {
      float w0 = rp[(size_t)k * 400];
#pragma unroll
      for (int s = 0; s < 8; ++s) acc[s] += w0 * av[s][k];
    }
#pragma unroll
    for (int s = 0; s < 8; ++s) pp[s][t] = acc[s];
  }
  __syncthreads();
  // --- wave-local softmax + write: wave w owns row w ---
  {
    float m = -INFINITY;
    for (int r = lane; r < 400; r += 64) m = fmaxf(m, pp[w][r]);
    m = wave_rmax(m);
    float sum = 0.f;
    for (int r = lane; r < 400; r += 64) {
      float e = expf(pp[w][r] - m);
      pp[w][r] = e;
      sum += e;
    }
    sum = wave_rsum(sum);
    float inv = 1.f / sum;
    for (int r = lane; r < 400; r += 64)
      out_ratt[(size_t)(b0 + w) * 400 + r] = pp[w][r] * inv;
  }
}

// ---------------------------------------------------------------------------
// scores: block per b; ent gather wave-per-action, 8 actions in flight;
// rel part via precomputed RX.
// ---------------------------------------------------------------------------
__global__ __launch_bounds__(512) void scores_kernel(
    const float* __restrict__ X2, const float* __restrict__ RX,
    const float* __restrict__ ent_emb, const int* __restrict__ r_space,
    const int* __restrict__ e_space, const float* __restrict__ mask,
    float* __restrict__ out_dist, float* __restrict__ out_ent) {
  int b = blockIdx.x;
  int t = threadIdx.x;
  int w = t >> 6, lane = t & 63;
  __shared__ float x2hi[200];
  __shared__ float scl[256];
  __shared__ float wr[8];
  if (t >= 200 && t < 400) x2hi[t - 200] = X2[(size_t)b * ADIMd + t];
  __syncthreads();
  const float4* xh = (const float4*)x2hi;
  // each wave: 32 actions, 8 at a time (8 gathers in flight)
  for (int i0 = 0; i0 < 32; i0 += 8) {
    int abase = w * 32 + i0;
    int ei[8];
#pragma unroll
    for (int u = 0; u < 8; ++u) ei[u] = e_space[(size_t)b * AA + abase + u];
    float p[8];
    if (lane < 50) {
      float4 xv = xh[lane];
#pragma unroll
      for (int u = 0; u < 8; ++u) {
        float4 vv = ((const float4*)(ent_emb + (size_t)ei[u] * ENTd))[lane];
        p[u] = dot4(vv, xv);
      }
    } else {
#pragma unroll
      for (int u = 0; u < 8; ++u) p[u] = 0.f;
    }
#pragma unroll
    for (int off = 32; off > 0; off >>= 1) {
#pragma unroll
      for (int u = 0; u < 8; ++u) p[u] += __shfl_xor(p[u], off);
    }
    if (lane == 0) {
#pragma unroll
      for (int u = 0; u < 8; ++u) scl[abase + u] = p[u];
    }
  }
  __syncthreads();
  float sc = -INFINITY;
  if (t < 256) {
    int r = r_space[(size_t)b * AA + t];
    sc = scl[t] + RX[(size_t)b * NRr + r] -
         (1.f - mask[(size_t)b * AA + t]) * 1e31f;
  }
  __syncthreads();
  if (w < 4) {
    float m = wave_rmax(sc);
    if (lane == 0) wr[w] = m;
  }
  __syncthreads();
  float gm = fmaxf(fmaxf(wr[0], wr[1]), fmaxf(wr[2], wr[3]));
  float e = (t < 256) ? expf(sc - gm) : 0.f;
  __syncthreads();
  if (w < 4) {
    float s2 = wave_rsum(e);
    if (lane == 0) wr[w] = s2;
  }
  __syncthreads();
  float gs = wr[0] + wr[1] + wr[2] + wr[3];
  float p = e / gs;
  if (t < 256) out_dist[(size_t)b * AA + t] = p;
  float ent = (t < 256) ? -p * logf(p + 1e-20f) : 0.f;
  __syncthreads();
  if (w < 4) {
    float s3 = wave_rsum(ent);
    if (lane == 0) wr[w] = s3;
  }
  __syncthreads();
  if (t == 0) out_ent[b] = wr[0] + wr[1] + wr[2] + wr[3];
}

// ---------------------------------------------------------------------------
extern "C" void kernel_launch(void* const* d_in, const int* in_sizes, int n_in,
                              void* d_out, int out_size, void* d_ws,
                              size_t ws_size, hipStream_t stream) {
  const float* H = (const float*)d_in[0];
  const float* mask = (const float*)d_in[1];
  const float* ent_emb = (const float*)d_in[2];
  const float* rel_emb = (const float*)d_in[3];
  const float* W1 = (const float*)d_in[4];
  const float* b1 = (const float*)d_in[5];
  const float* W2 = (const float*)d_in[6];
  const float* b2 = (const float*)d_in[7];
  const float* W3 = (const float*)d_in[8];
  const float* b3 = (const float*)d_in[9];
  const float* W4 = (const float*)d_in[10];
  const float* b4 = (const float*)d_in[11];
  const float* W5 = (const float*)d_in[12];
  const float* b5 = (const float*)d_in[13];
  const float* W6 = (const float*)d_in[14];
  const float* b6 = (const float*)d_in[15];
  const float* Watt = (const float*)d_in[16];
  const float* batt = (const float*)d_in[17];
  const int* e_idx = (const int*)d_in[18];
  const int* q_idx = (const int*)d_in[19];
  const int* pred_id = (const int*)d_in[20];
  const int* r_space = (const int*)d_in[21];
  const int* e_space = (const int*)d_in[22];

  float* ws = (float*)d_ws;
  float* RK = ws;                   // 80000
  float* S_T = ws + 80000;          // 80000  [200][400]
  float* cvec = ws + 160000;        // 512
  float* P = ws + 160512;           // 40000
  float* Q_T = ws + 200512;         // 40000  [200][200]
  float* W6bb = ws + 240512;        // 40000
  float* REatt = ws + 280512;       // 80000  [400][200]
  float* relT = ws + 360512;        // 80000  [200][400]
  float* WaT = ws + 440512;         // 80000  [400][200]
  float* W1T = ws + 520512;         // 320000 [800][400]
  float* W2T = ws + 840512;         // 160000 [400][400]
  float* ab = ws + 1000512;         // 256
  float* v1 = ws + 1000768;         // 256
  float* X = ws + 1001024;          // 204800
  float* X2 = ws + 1205824;         // 204800
  float* RX = ws + 1410624;         // 204800 [512][400]

  float* out = (float*)d_out;
  float* out_dist = out;                 // [512,256]
  float* out_ent = out + BB * AA;        // [512]
  float* out_ratt = out + BB * AA + BB;  // [512,400]

  hipLaunchKernelGGL(prep1_kernel, dim3(297), dim3(256), 0, stream, rel_emb,
                     W4, b4, W5, b5, W6, Watt, W1, W2, RK, P, W6bb, ab, relT,
                     WaT, W1T, W2T);
  hipLaunchKernelGGL(prep2_kernel, dim3(126), dim3(256), 0, stream, rel_emb,
                     W3, b3, W6, Watt, batt, b6, RK, P, W6bb, ab, S_T, cvec,
                     Q_T, REatt, v1);
  hipLaunchKernelGGL(x1_kernel, dim3(64), dim3(512), 0, stream, ent_emb,
                     rel_emb, H, e_idx, q_idx, W1T, b1, X);
  hipLaunchKernelGGL(x2rx_kernel, dim3(64), dim3(512), 0, stream, X, W2T, b2,
                     relT, X2, RX);
  hipLaunchKernelGGL(fused_mid_kernel, dim3(64), dim3(512), 0, stream,
                     ent_emb, pred_id, X2, S_T, cvec, Q_T, REatt, relT, WaT,
                     v1, out_ratt);
  hipLaunchKernelGGL(scores_kernel, dim3(512), dim3(512), 0, stream, X2, RX,
                     ent_emb, r_space, e_space, mask, out_dist, out_ent);
}

// Round 9
// 157.311 us; speedup vs baseline: 1.6082x; 1.6082x over previous
//
#include <hip/hip_runtime.h>
#include <cstdint>
#include <cstddef>

#define BB 512
#define NEn 100000
#define NRr 400
#define AA 256
#define ENTd 200
#define RELd 200
#define HISTd 400
#define ADIMd 400

__device__ __forceinline__ float dot4(const float4 a, const float4 b) {
  return a.x * b.x + a.y * b.y + a.z * b.z + a.w * b.w;
}
__device__ __forceinline__ float wave_rmax(float v) {
#pragma unroll
  for (int off = 32; off > 0; off >>= 1) v = fmaxf(v, __shfl_xor(v, off));
  return v;
}
__device__ __forceinline__ float wave_rsum(float v) {
#pragma unroll
  for (int off = 32; off > 0; off >>= 1) v += __shfl_xor(v, off);
  return v;
}

// ---------------------------------------------------------------------------
// prep1: RK, P, W6bb, ab + tiled transposes relT/WaT/W1T/W2T
// ---------------------------------------------------------------------------
__global__ __launch_bounds__(256) void prep1_kernel(
    const float* __restrict__ rel_emb, const float* __restrict__ W4,
    const float* __restrict__ b4, const float* __restrict__ W5,
    const float* __restrict__ b5, const float* __restrict__ W6,
    const float* __restrict__ Watt, const float* __restrict__ W1,
    const float* __restrict__ W2, float* __restrict__ RK,
    float* __restrict__ P, float* __restrict__ W6bb, float* __restrict__ ab,
    float* __restrict__ relT, float* __restrict__ WaT,
    float* __restrict__ W1T, float* __restrict__ W2T) {
  int t = threadIdx.x;
  int blk = blockIdx.x;
  if (blk == 0) {
    __shared__ float rs[RELd];
    if (t < RELd) {
      float s = 0.f;
      for (int r = 0; r < NRr; r += 4) {
        s += rel_emb[(size_t)r * RELd + t] + rel_emb[(size_t)(r + 1) * RELd + t] +
             rel_emb[(size_t)(r + 2) * RELd + t] + rel_emb[(size_t)(r + 3) * RELd + t];
      }
      rs[t] = s;
    }
    __syncthreads();
    if (t < RELd) {
      float acc = b5[t];
      const float4* w = (const float4*)(W5 + (size_t)t * 400);
      const float4* rv = (const float4*)rs;
      for (int k = 0; k < 50; ++k) acc += dot4(w[k], rv[k]);
      ab[t] = acc;
    }
  } else if (blk <= 50) {
    int r0 = (blk - 1) * 8;
    __shared__ float re[8][RELd];
    for (int i = t; i < 8 * RELd; i += 256)
      re[i / RELd][i % RELd] = rel_emb[(size_t)(r0 + i / RELd) * RELd + i % RELd];
    __syncthreads();
    if (t < RELd) {
      float bv = b4[t];
      float acc[8];
#pragma unroll
      for (int s = 0; s < 8; ++s) acc[s] = bv;
      const float4* w = (const float4*)(W4 + (size_t)t * RELd);
      for (int k = 0; k < 50; ++k) {
        float4 wv = w[k];
#pragma unroll
        for (int s = 0; s < 8; ++s) acc[s] += dot4(wv, ((const float4*)re[s])[k]);
      }
#pragma unroll
      for (int s = 0; s < 8; ++s) RK[(size_t)(r0 + s) * RELd + t] = acc[s];
    }
  } else if (blk <= 75) {
    int i0 = (blk - 51) * 8;
    __shared__ float w6s[8][200];
    for (int i = t; i < 8 * 200; i += 256)
      w6s[i / 200][i % 200] = W6[(size_t)(i0 + i / 200) * 400 + i % 200];
    __syncthreads();
    if (t < 200) {
      int k = t;
      float acc[8] = {0, 0, 0, 0, 0, 0, 0, 0};
      for (int j = 0; j < 200; j += 4) {
        float r0v = W5[(size_t)j * 400 + 200 + k];
        float r1v = W5[(size_t)(j + 1) * 400 + 200 + k];
        float r2v = W5[(size_t)(j + 2) * 400 + 200 + k];
        float r3v = W5[(size_t)(j + 3) * 400 + 200 + k];
#pragma unroll
        for (int s = 0; s < 8; ++s)
          acc[s] += w6s[s][j] * r0v + w6s[s][j + 1] * r1v + w6s[s][j + 2] * r2v +
                    w6s[s][j + 3] * r3v;
      }
#pragma unroll
      for (int s = 0; s < 8; ++s) P[(size_t)(i0 + s) * 200 + k] = 400.f * acc[s];
    }
  } else if (blk <= 100) {
    int u0 = (blk - 76) * 8;
    __shared__ float wbs[8][200];
    for (int i = t; i < 8 * 200; i += 256)
      wbs[i / 200][i % 200] = Watt[(size_t)(u0 + i / 200) * 600 + 400 + i % 200];
    __syncthreads();
    if (t < 200) {
      int j = t;
      float acc[8] = {0, 0, 0, 0, 0, 0, 0, 0};
      for (int i = 0; i < 200; i += 4) {
        float r0v = W6[(size_t)i * 400 + 200 + j];
        float r1v = W6[(size_t)(i + 1) * 400 + 200 + j];
        float r2v = W6[(size_t)(i + 2) * 400 + 200 + j];
        float r3v = W6[(size_t)(i + 3) * 400 + 200 + j];
#pragma unroll
        for (int s = 0; s < 8; ++s)
          acc[s] += wbs[s][i] * r0v + wbs[s][i + 1] * r1v + wbs[s][i + 2] * r2v +
                    wbs[s][i + 3] * r3v;
      }
#pragma unroll
      for (int s = 0; s < 8; ++s) W6bb[(size_t)(u0 + s) * 200 + j] = acc[s];
    }
  } else {
    __shared__ float tlds[64][65];
    int tb = blk - 101;
    const float* src;
    float* dst;
    int M, N, LD, ti, tj;
    if (tb < 28) {
      src = rel_emb; dst = relT; M = 400; N = 200; LD = 200;
      ti = tb / 4; tj = tb % 4;
    } else if (tb < 56) {
      tb -= 28;
      src = Watt; dst = WaT; M = 200; N = 400; LD = 600;
      ti = tb / 7; tj = tb % 7;
    } else if (tb < 147) {
      tb -= 56;
      src = W1; dst = W1T; M = 400; N = 800; LD = 800;
      ti = tb / 13; tj = tb % 13;
    } else {
      tb -= 147;
      src = W2; dst = W2T; M = 400; N = 400; LD = 400;
      ti = tb / 7; tj = tb % 7;
    }
    int i0 = ti * 64, j0 = tj * 64;
    for (int idx = t; idx < 4096; idx += 256) {
      int r = idx >> 6, c = idx & 63;
      int i = i0 + r, j = j0 + c;
      if (i < M && j < N) tlds[r][c] = src[(size_t)i * LD + j];
    }
    __syncthreads();
    for (int idx = t; idx < 4096; idx += 256) {
      int r = idx >> 6, c = idx & 63;
      int j = j0 + r, i = i0 + c;
      if (i < M && j < N) dst[(size_t)j * M + i] = tlds[c][r];
    }
  }
}

// ---------------------------------------------------------------------------
// prep2: S_T, cvec, Q_T, REatt, v1 (unchanged)
// ---------------------------------------------------------------------------
__global__ __launch_bounds__(256) void prep2_kernel(
    const float* __restrict__ rel_emb, const float* __restrict__ W3,
    const float* __restrict__ b3, const float* __restrict__ W6,
    const float* __restrict__ Watt, const float* __restrict__ batt,
    const float* __restrict__ b6, const float* __restrict__ RK,
    const float* __restrict__ P, const float* __restrict__ W6bb,
    const float* __restrict__ ab, float* __restrict__ S_T,
    float* __restrict__ cvec, float* __restrict__ Q_T,
    float* __restrict__ REatt, float* __restrict__ v1) {
  int t = threadIdx.x;
  int blk = blockIdx.x;
  if (blk < 50) {
    int r0 = blk * 8;
    __shared__ float rks[8][200];
    __shared__ float b3s[200];
    for (int i = t; i < 8 * 200; i += 256)
      rks[i / 200][i % 200] = RK[(size_t)(r0 + i / 200) * 200 + i % 200];
    if (t < 200) b3s[t] = b3[t];
    __syncthreads();
    if (t < 200) {
      int i = t;
      float acc[8] = {0, 0, 0, 0, 0, 0, 0, 0};
      for (int j = 0; j < 200; j += 4) {
        float w0 = W3[(size_t)j * 200 + i];
        float w1 = W3[(size_t)(j + 1) * 200 + i];
        float w2 = W3[(size_t)(j + 2) * 200 + i];
        float w3v = W3[(size_t)(j + 3) * 200 + i];
#pragma unroll
        for (int s = 0; s < 8; ++s)
          acc[s] += w0 * rks[s][j] + w1 * rks[s][j + 1] + w2 * rks[s][j + 2] +
                    w3v * rks[s][j + 3];
      }
      float4 s0 = make_float4(acc[0], acc[1], acc[2], acc[3]);
      float4 s1 = make_float4(acc[4], acc[5], acc[6], acc[7]);
      *(float4*)(S_T + (size_t)i * 400 + r0) = s0;
      *(float4*)(S_T + (size_t)i * 400 + r0 + 4) = s1;
    }
    {
      int w = t >> 6, lane = t & 63;
      float p0 = 0.f, p1 = 0.f;
      for (int j = lane; j < 200; j += 64) {
        p0 += b3s[j] * rks[w][j];
        p1 += b3s[j] * rks[w + 4][j];
      }
      p0 = wave_rsum(p0);
      p1 = wave_rsum(p1);
      if (lane == 0) {
        cvec[r0 + w] = p0;
        cvec[r0 + w + 4] = p1;
      }
    }
  } else if (blk < 75) {
    int u0 = (blk - 50) * 8;
    __shared__ float wbs[8][200];
    for (int i = t; i < 8 * 200; i += 256)
      wbs[i / 200][i % 200] = Watt[(size_t)(u0 + i / 200) * 600 + 400 + i % 200];
    __syncthreads();
    if (t < 200) {
      int k = t;
      float acc[8] = {0, 0, 0, 0, 0, 0, 0, 0};
      for (int i = 0; i < 200; i += 4) {
        float r0v = P[(size_t)i * 200 + k];
        float r1v = P[(size_t)(i + 1) * 200 + k];
        float r2v = P[(size_t)(i + 2) * 200 + k];
        float r3v = P[(size_t)(i + 3) * 200 + k];
#pragma unroll
        for (int s = 0; s < 8; ++s)
          acc[s] += wbs[s][i] * r0v + wbs[s][i + 1] * r1v + wbs[s][i + 2] * r2v +
                    wbs[s][i + 3] * r3v;
      }
      float4 s0 = make_float4(acc[0], acc[1], acc[2], acc[3]);
      float4 s1 = make_float4(acc[4], acc[5], acc[6], acc[7]);
      *(float4*)(Q_T + (size_t)k * 200 + u0) = s0;
      *(float4*)(Q_T + (size_t)k * 200 + u0 + 4) = s1;
    }
  } else if (blk < 125) {
    int r0 = (blk - 75) * 8;
    __shared__ float rels[8][200];
    for (int i = t; i < 8 * 200; i += 256)
      rels[i / 200][i % 200] = rel_emb[(size_t)(r0 + i / 200) * 200 + i % 200];
    __syncthreads();
    if (t < 200) {
      float acc[8] = {0, 0, 0, 0, 0, 0, 0, 0};
      const float4* w = (const float4*)(W6bb + (size_t)t * 200);
      for (int k = 0; k < 50; ++k) {
        float4 wv = w[k];
#pragma unroll
        for (int s = 0; s < 8; ++s) acc[s] += dot4(wv, ((const float4*)rels[s])[k]);
      }
#pragma unroll
      for (int s = 0; s < 8; ++s) REatt[(size_t)(r0 + s) * 200 + t] = acc[s];
    }
  } else {
    __shared__ float abs_[200];
    __shared__ float us[200];
    if (t < 200) abs_[t] = ab[t];
    __syncthreads();
    if (t < 200) {
      float u = b6[t];
      const float4* w = (const float4*)(W6 + (size_t)t * 400);
      const float4* rv = (const float4*)abs_;
      for (int k = 0; k < 50; ++k) u += dot4(w[k], rv[k]);
      us[t] = u;
    }
    __syncthreads();
    if (t < 200) {
      float v = batt[t];
      const float4* w = (const float4*)(Watt + (size_t)t * 600 + 400);
      const float4* rv = (const float4*)us;
      for (int k = 0; k < 50; ++k) v += dot4(w[k], rv[k]);
      v1[t] = v;
    }
  }
}

// ---------------------------------------------------------------------------
// x1: X = relu(W1T^T . cat(E,H,Q) + b1)
// 1024 threads, R=2, grid 256, 2-way k-split + LDS combine
// ---------------------------------------------------------------------------
__global__ __launch_bounds__(1024) void x1_kernel(
    const float* __restrict__ ent_emb, const float* __restrict__ rel_emb,
    const float* __restrict__ H, const int* __restrict__ e_idx,
    const int* __restrict__ q_idx, const float* __restrict__ W1T,
    const float* __restrict__ b1, float* __restrict__ X) {
  int b0 = blockIdx.x * 2;
  int t = threadIdx.x;
  __shared__ float cv[2][800];
  __shared__ float prt[2][2][400];  // [h][s][j]
  for (int i = t; i < 1600; i += 1024) {
    int s = i / 800, k = i % 800;
    float v;
    if (k < ENTd)
      v = ent_emb[(size_t)e_idx[b0 + s] * ENTd + k];
    else if (k < ENTd + HISTd)
      v = H[(size_t)(b0 + s) * HISTd + (k - ENTd)];
    else
      v = rel_emb[(size_t)q_idx[b0 + s] * RELd + (k - ENTd - HISTd)];
    cv[s][k] = v;
  }
  __syncthreads();
  if (t < 800) {
    int j = t % 400, h = t / 400;
    float a0 = 0.f, a1 = 0.f;
    const float* wp = W1T + j;
    int k0 = h * 400;
#pragma unroll 4
    for (int k = k0; k < k0 + 400; ++k) {
      float w0 = wp[(size_t)k * 400];
      a0 += w0 * cv[0][k];
      a1 += w0 * cv[1][k];
    }
    prt[h][0][j] = a0;
    prt[h][1][j] = a1;
  }
  __syncthreads();
  if (t < 800) {
    int s = t / 400, j = t % 400;
    X[(size_t)(b0 + s) * ADIMd + j] =
        fmaxf(b1[j] + prt[0][s][j] + prt[1][s][j], 0.f);
  }
}

// ---------------------------------------------------------------------------
// x2rx: X2 = W2T^T . X + b2 ; RX[b][r] = rel_emb[r] . X2[b][:200]
// 1024 threads, R=2, grid 256, 2-way k-split
// ---------------------------------------------------------------------------
__global__ __launch_bounds__(1024) void x2rx_kernel(
    const float* __restrict__ X, const float* __restrict__ W2T,
    const float* __restrict__ b2, const float* __restrict__ relT,
    float* __restrict__ X2, float* __restrict__ RX) {
  int b0 = blockIdx.x * 2;
  int t = threadIdx.x;
  __shared__ float cv[2][400];
  __shared__ float prt[2][2][400];
  __shared__ float x2lo[2][200];
  for (int i = t; i < 800; i += 1024) cv[i / 400][i % 400] = X[(size_t)b0 * 400 + i];
  __syncthreads();
  if (t < 800) {
    int j = t % 400, h = t / 400;
    float a0 = 0.f, a1 = 0.f;
    const float* wp = W2T + j;
    int k0 = h * 200;
#pragma unroll 4
    for (int k = k0; k < k0 + 200; ++k) {
      float w0 = wp[(size_t)k * 400];
      a0 += w0 * cv[0][k];
      a1 += w0 * cv[1][k];
    }
    prt[h][0][j] = a0;
    prt[h][1][j] = a1;
  }
  __syncthreads();
  if (t < 800) {
    int s = t / 400, j = t % 400;
    float v = b2[j] + prt[0][s][j] + prt[1][s][j];
    X2[(size_t)(b0 + s) * ADIMd + j] = v;
    if (j < 200) x2lo[s][j] = v;
  }
  __syncthreads();
  if (t < 800) {
    int r = t % 400, h = t / 400;
    const float* rp = relT + r;
    float a0 = 0.f, a1 = 0.f;
    int k0 = h * 100;
#pragma unroll 4
    for (int k = k0; k < k0 + 100; ++k) {
      float w0 = rp[(size_t)k * 400];
      a0 += w0 * x2lo[0][k];
      a1 += w0 * x2lo[1][k];
    }
    prt[h][0][r] = a0;
    prt[h][1][r] = a1;
  }
  __syncthreads();
  if (t < 800) {
    int s = t / 400, r = t % 400;
    RX[(size_t)(b0 + s) * NRr + r] = prt[0][s][r] + prt[1][s][r];
  }
}

// ---------------------------------------------------------------------------
// fused_mid: 1024 threads, R=2, grid 256; k-split phases + LDS combine;
// softmax with 8 waves/row.
// ---------------------------------------------------------------------------
__global__ __launch_bounds__(1024) void fused_mid_kernel(
    const float* __restrict__ ent_emb, const int* __restrict__ pred_id,
    const float* __restrict__ X2, const float* __restrict__ S_T,
    const float* __restrict__ cvec, const float* __restrict__ Q_T,
    const float* __restrict__ REatt, const float* __restrict__ relT,
    const float* __restrict__ WaT, const float* __restrict__ v1c,
    float* __restrict__ out_ratt) {
  int b0 = blockIdx.x * 2;
  int t = threadIdx.x;
  int w = t >> 6, lane = t & 63;
  __shared__ float pes[2][200];
  __shared__ float x2s[2][400];
  __shared__ float pp[2][400];
  __shared__ float av[2][200];
  __shared__ float prt[1600];  // la/logits: [(h*2+s)*400+r] ; attv: [(h*2+s)*200+j]
  __shared__ float wred[2][8];
  if (t < 400)
    pes[t / 200][t % 200] = ent_emb[(size_t)pred_id[b0 + t / 200] * ENTd + t % 200];
  else if (t >= 512 && t < 512 + 800) {
    int i = t - 512;
    x2s[i / 400][i % 400] = X2[(size_t)b0 * 400 + i];
  }
  __syncthreads();
  // --- la: 2-way k-split ---
  if (t < 800) {
    int r = t % 400, h = t / 400;
    float a0 = 0.f, a1 = 0.f;
    const float* sp = S_T + r;
    int k0 = h * 100;
#pragma unroll 4
    for (int k = k0; k < k0 + 100; ++k) {
      float w0 = sp[(size_t)k * 400];
      a0 += w0 * pes[0][k];
      a1 += w0 * pes[1][k];
    }
    prt[(h * 2 + 0) * 400 + r] = a0;
    prt[(h * 2 + 1) * 400 + r] = a1;
  }
  __syncthreads();
  if (t < 800) {
    int s = t / 400, r = t % 400;
    pp[s][r] = cvec[r] + prt[(0 * 2 + s) * 400 + r] + prt[(1 * 2 + s) * 400 + r];
  }
  __syncthreads();
  int row = w >> 3, q = w & 7;  // 8 waves per batch row
  // --- softmax(pp rows) ---
  {
    int r = q * 64 + lane;
    float m = (r < 400) ? pp[row][r] : -INFINITY;
    m = wave_rmax(m);
    if (lane == 0) wred[row][q] = m;
    __syncthreads();
    float gm = wred[row][0];
#pragma unroll
    for (int i = 1; i < 8; ++i) gm = fmaxf(gm, wred[row][i]);
    __syncthreads();
    float e = 0.f;
    if (r < 400) {
      e = expf(pp[row][r] - gm);
      pp[row][r] = e;
    }
    float sum = wave_rsum(e);
    if (lane == 0) wred[row][q] = sum;
    __syncthreads();
    float gs = 0.f;
#pragma unroll
    for (int i = 0; i < 8; ++i) gs += wred[row][i];
    float inv = 1.f / gs;
    if (r < 400) pp[row][r] *= inv;
  }
  __syncthreads();
  // --- attv: 4-way k-split, j = t%200, h = (t/200)&3 ---
  if (t < 800) {
    int j = t % 200, h = t / 200;
    float a0, a1;
    if (h == 0) {
      float v = v1c[j];
      a0 = v; a1 = v;
    } else {
      a0 = 0.f; a1 = 0.f;
    }
    {  // WaT: k in [h*100, h*100+100)
      const float* wp = WaT + (size_t)(h * 100) * 200 + j;
      int kb = h * 100;
#pragma unroll 4
      for (int k = 0; k < 100; ++k) {
        float w0 = wp[(size_t)k * 200];
        a0 += w0 * x2s[0][kb + k];
        a1 += w0 * x2s[1][kb + k];
      }
    }
    {  // Q_T: k in [h*50, h*50+50)
      const float* qp = Q_T + (size_t)(h * 50) * 200 + j;
      int kb = h * 50;
#pragma unroll 4
      for (int k = 0; k < 50; ++k) {
        float w0 = qp[(size_t)k * 200];
        a0 += w0 * pes[0][kb + k];
        a1 += w0 * pes[1][kb + k];
      }
    }
    {  // REatt: r in [h*100, h*100+100)
      const float* rp = REatt + (size_t)(h * 100) * 200 + j;
      int rb = h * 100;
#pragma unroll 4
      for (int r = 0; r < 100; ++r) {
        float w0 = rp[(size_t)r * 200];
        a0 += w0 * pp[0][rb + r];
        a1 += w0 * pp[1][rb + r];
      }
    }
    prt[(h * 2 + 0) * 200 + j] = a0;
    prt[(h * 2 + 1) * 200 + j] = a1;
  }
  __syncthreads();
  if (t < 400) {
    int s = t / 200, j = t % 200;
    av[s][j] = prt[(0 * 2 + s) * 200 + j] + prt[(1 * 2 + s) * 200 + j] +
               prt[(2 * 2 + s) * 200 + j] + prt[(3 * 2 + s) * 200 + j];
  }
  __syncthreads();
  // --- logits: 2-way k-split ---
  if (t < 800) {
    int r = t % 400, h = t / 400;
    const float* rp = relT + r;
    float a0 = 0.f, a1 = 0.f;
    int k0 = h * 100;
#pragma unroll 4
    for (int k = k0; k < k0 + 100; ++k) {
      float w0 = rp[(size_t)k * 400];
      a0 += w0 * av[0][k];
      a1 += w0 * av[1][k];
    }
    prt[(h * 2 + 0) * 400 + r] = a0;
    prt[(h * 2 + 1) * 400 + r] = a1;
  }
  __syncthreads();
  if (t < 800) {
    int s = t / 400, r = t % 400;
    pp[s][r] = prt[(0 * 2 + s) * 400 + r] + prt[(1 * 2 + s) * 400 + r];
  }
  __syncthreads();
  // --- softmax + write ---
  {
    int r = q * 64 + lane;
    float m = (r < 400) ? pp[row][r] : -INFINITY;
    m = wave_rmax(m);
    if (lane == 0) wred[row][q] = m;
    __syncthreads();
    float gm = wred[row][0];
#pragma unroll
    for (int i = 1; i < 8; ++i) gm = fmaxf(gm, wred[row][i]);
    __syncthreads();
    float e = 0.f;
    if (r < 400) {
      e = expf(pp[row][r] - gm);
    }
    float sum = wave_rsum(e);
    if (lane == 0) wred[row][q] = sum;
    __syncthreads();
    float gs = 0.f;
#pragma unroll
    for (int i = 0; i < 8; ++i) gs += wred[row][i];
    float inv = 1.f / gs;
    if (r < 400) out_ratt[(size_t)(b0 + row) * 400 + r] = e * inv;
  }
}

// ---------------------------------------------------------------------------
// scores: block per b; ent gather wave-per-action, 8 actions in flight;
// rel part via precomputed RX.
// ---------------------------------------------------------------------------
__global__ __launch_bounds__(512) void scores_kernel(
    const float* __restrict__ X2, const float* __restrict__ RX,
    const float* __restrict__ ent_emb, const int* __restrict__ r_space,
    const int* __restrict__ e_space, const float* __restrict__ mask,
    float* __restrict__ out_dist, float* __restrict__ out_ent) {
  int b = blockIdx.x;
  int t = threadIdx.x;
  int w = t >> 6, lane = t & 63;
  __shared__ float x2hi[200];
  __shared__ float scl[256];
  __shared__ float wr[8];
  if (t >= 200 && t < 400) x2hi[t - 200] = X2[(size_t)b * ADIMd + t];
  __syncthreads();
  const float4* xh = (const float4*)x2hi;
  for (int i0 = 0; i0 < 32; i0 += 8) {
    int abase = w * 32 + i0;
    int ei[8];
#pragma unroll
    for (int u = 0; u < 8; ++u) ei[u] = e_space[(size_t)b * AA + abase + u];
    float p[8];
    if (lane < 50) {
      float4 xv = xh[lane];
#pragma unroll
      for (int u = 0; u < 8; ++u) {
        float4 vv = ((const float4*)(ent_emb + (size_t)ei[u] * ENTd))[lane];
        p[u] = dot4(vv, xv);
      }
    } else {
#pragma unroll
      for (int u = 0; u < 8; ++u) p[u] = 0.f;
    }
#pragma unroll
    for (int off = 32; off > 0; off >>= 1) {
#pragma unroll
      for (int u = 0; u < 8; ++u) p[u] += __shfl_xor(p[u], off);
    }
    if (lane == 0) {
#pragma unroll
      for (int u = 0; u < 8; ++u) scl[abase + u] = p[u];
    }
  }
  __syncthreads();
  float sc = -INFINITY;
  if (t < 256) {
    int r = r_space[(size_t)b * AA + t];
    sc = scl[t] + RX[(size_t)b * NRr + r] -
         (1.f - mask[(size_t)b * AA + t]) * 1e31f;
  }
  __syncthreads();
  if (w < 4) {
    float m = wave_rmax(sc);
    if (lane == 0) wr[w] = m;
  }
  __syncthreads();
  float gm = fmaxf(fmaxf(wr[0], wr[1]), fmaxf(wr[2], wr[3]));
  float e = (t < 256) ? expf(sc - gm) : 0.f;
  __syncthreads();
  if (w < 4) {
    float s2 = wave_rsum(e);
    if (lane == 0) wr[w] = s2;
  }
  __syncthreads();
  float gs = wr[0] + wr[1] + wr[2] + wr[3];
  float p = e / gs;
  if (t < 256) out_dist[(size_t)b * AA + t] = p;
  float ent = (t < 256) ? -p * logf(p + 1e-20f) : 0.f;
  __syncthreads();
  if (w < 4) {
    float s3 = wave_rsum(ent);
    if (lane == 0) wr[w] = s3;
  }
  __syncthreads();
  if (t == 0) out_ent[b] = wr[0] + wr[1] + wr[2] + wr[3];
}

// ---------------------------------------------------------------------------
extern "C" void kernel_launch(void* const* d_in, const int* in_sizes, int n_in,
                              void* d_out, int out_size, void* d_ws,
                              size_t ws_size, hipStream_t stream) {
  const float* H = (const float*)d_in[0];
  const float* mask = (const float*)d_in[1];
  const float* ent_emb = (const float*)d_in[2];
  const float* rel_emb = (const float*)d_in[3];
  const float* W1 = (const float*)d_in[4];
  const float* b1 = (const float*)d_in[5];
  const float* W2 = (const float*)d_in[6];
  const float* b2 = (const float*)d_in[7];
  const float* W3 = (const float*)d_in[8];
  const float* b3 = (const float*)d_in[9];
  const float* W4 = (const float*)d_in[10];
  const float* b4 = (const float*)d_in[11];
  const float* W5 = (const float*)d_in[12];
  const float* b5 = (const float*)d_in[13];
  const float* W6 = (const float*)d_in[14];
  const float* b6 = (const float*)d_in[15];
  const float* Watt = (const float*)d_in[16];
  const float* batt = (const float*)d_in[17];
  const int* e_idx = (const int*)d_in[18];
  const int* q_idx = (const int*)d_in[19];
  const int* pred_id = (const int*)d_in[20];
  const int* r_space = (const int*)d_in[21];
  const int* e_space = (const int*)d_in[22];

  float* ws = (float*)d_ws;
  float* RK = ws;                   // 80000
  float* S_T = ws + 80000;          // 80000  [200][400]
  float* cvec = ws + 160000;        // 512
  float* P = ws + 160512;           // 40000
  float* Q_T = ws + 200512;         // 40000  [200][200]
  float* W6bb = ws + 240512;        // 40000
  float* REatt = ws + 280512;       // 80000  [400][200]
  float* relT = ws + 360512;        // 80000  [200][400]
  float* WaT = ws + 440512;         // 80000  [400][200]
  float* W1T = ws + 520512;         // 320000 [800][400]
  float* W2T = ws + 840512;         // 160000 [400][400]
  float* ab = ws + 1000512;         // 256
  float* v1 = ws + 1000768;         // 256
  float* X = ws + 1001024;          // 204800
  float* X2 = ws + 1205824;         // 204800
  float* RX = ws + 1410624;         // 204800 [512][400]

  float* out = (float*)d_out;
  float* out_dist = out;                 // [512,256]
  float* out_ent = out + BB * AA;        // [512]
  float* out_ratt = out + BB * AA + BB;  // [512,400]

  hipLaunchKernelGGL(prep1_kernel, dim3(297), dim3(256), 0, stream, rel_emb,
                     W4, b4, W5, b5, W6, Watt, W1, W2, RK, P, W6bb, ab, relT,
                     WaT, W1T, W2T);
  hipLaunchKernelGGL(prep2_kernel, dim3(126), dim3(256), 0, stream, rel_emb,
                     W3, b3, W6, Watt, batt, b6, RK, P, W6bb, ab, S_T, cvec,
                     Q_T, REatt, v1);
  hipLaunchKernelGGL(x1_kernel, dim3(256), dim3(1024), 0, stream, ent_emb,
                     rel_emb, H, e_idx, q_idx, W1T, b1, X);
  hipLaunchKernelGGL(x2rx_kernel, dim3(256), dim3(1024), 0, stream, X, W2T,
                     b2, relT, X2, RX);
  hipLaunchKernelGGL(fused_mid_kernel, dim3(256), dim3(1024), 0, stream,
                     ent_emb, pred_id, X2, S_T, cvec, Q_T, REatt, relT, WaT,
                     v1, out_ratt);
  hipLaunchKernelGGL(scores_kernel, dim3(512), dim3(512), 0, stream, X2, RX,
                     ent_emb, r_space, e_space, mask, out_dist, out_ent);
}

// Round 10
// 136.395 us; speedup vs baseline: 1.8549x; 1.1533x over previous
//
#include <hip/hip_runtime.h>
#include <cstdint>
#include <cstddef>

#define BB 512
#define NEn 100000
#define NRr 400
#define AA 256
#define ENTd 200
#define RELd 200
#define HISTd 400
#define ADIMd 400

__device__ __forceinline__ float dot4(const float4 a, const float4 b) {
  return a.x * b.x + a.y * b.y + a.z * b.z + a.w * b.w;
}
__device__ __forceinline__ float wave_rmax(float v) {
#pragma unroll
  for (int off = 32; off > 0; off >>= 1) v = fmaxf(v, __shfl_xor(v, off));
  return v;
}
__device__ __forceinline__ float wave_rsum(float v) {
#pragma unroll
  for (int off = 32; off > 0; off >>= 1) v += __shfl_xor(v, off);
  return v;
}

// ---------------------------------------------------------------------------
// prep1: RK, P, W6bb, ab + tiled transposes relT/WaT/W1T/W2T  (unchanged)
// ---------------------------------------------------------------------------
__global__ __launch_bounds__(256) void prep1_kernel(
    const float* __restrict__ rel_emb, const float* __restrict__ W4,
    const float* __restrict__ b4, const float* __restrict__ W5,
    const float* __restrict__ b5, const float* __restrict__ W6,
    const float* __restrict__ Watt, const float* __restrict__ W1,
    const float* __restrict__ W2, float* __restrict__ RK,
    float* __restrict__ P, float* __restrict__ W6bb, float* __restrict__ ab,
    float* __restrict__ relT, float* __restrict__ WaT,
    float* __restrict__ W1T, float* __restrict__ W2T) {
  int t = threadIdx.x;
  int blk = blockIdx.x;
  if (blk == 0) {
    __shared__ float rs[RELd];
    if (t < RELd) {
      float s = 0.f;
      for (int r = 0; r < NRr; r += 4) {
        s += rel_emb[(size_t)r * RELd + t] + rel_emb[(size_t)(r + 1) * RELd + t] +
             rel_emb[(size_t)(r + 2) * RELd + t] + rel_emb[(size_t)(r + 3) * RELd + t];
      }
      rs[t] = s;
    }
    __syncthreads();
    if (t < RELd) {
      float acc = b5[t];
      const float4* w = (const float4*)(W5 + (size_t)t * 400);
      const float4* rv = (const float4*)rs;
      for (int k = 0; k < 50; ++k) acc += dot4(w[k], rv[k]);
      ab[t] = acc;
    }
  } else if (blk <= 50) {
    int r0 = (blk - 1) * 8;
    __shared__ float re[8][RELd];
    for (int i = t; i < 8 * RELd; i += 256)
      re[i / RELd][i % RELd] = rel_emb[(size_t)(r0 + i / RELd) * RELd + i % RELd];
    __syncthreads();
    if (t < RELd) {
      float bv = b4[t];
      float acc[8];
#pragma unroll
      for (int s = 0; s < 8; ++s) acc[s] = bv;
      const float4* w = (const float4*)(W4 + (size_t)t * RELd);
      for (int k = 0; k < 50; ++k) {
        float4 wv = w[k];
#pragma unroll
        for (int s = 0; s < 8; ++s) acc[s] += dot4(wv, ((const float4*)re[s])[k]);
      }
#pragma unroll
      for (int s = 0; s < 8; ++s) RK[(size_t)(r0 + s) * RELd + t] = acc[s];
    }
  } else if (blk <= 75) {
    int i0 = (blk - 51) * 8;
    __shared__ float w6s[8][200];
    for (int i = t; i < 8 * 200; i += 256)
      w6s[i / 200][i % 200] = W6[(size_t)(i0 + i / 200) * 400 + i % 200];
    __syncthreads();
    if (t < 200) {
      int k = t;
      float acc[8] = {0, 0, 0, 0, 0, 0, 0, 0};
      for (int j = 0; j < 200; j += 4) {
        float r0v = W5[(size_t)j * 400 + 200 + k];
        float r1v = W5[(size_t)(j + 1) * 400 + 200 + k];
        float r2v = W5[(size_t)(j + 2) * 400 + 200 + k];
        float r3v = W5[(size_t)(j + 3) * 400 + 200 + k];
#pragma unroll
        for (int s = 0; s < 8; ++s)
          acc[s] += w6s[s][j] * r0v + w6s[s][j + 1] * r1v + w6s[s][j + 2] * r2v +
                    w6s[s][j + 3] * r3v;
      }
#pragma unroll
      for (int s = 0; s < 8; ++s) P[(size_t)(i0 + s) * 200 + k] = 400.f * acc[s];
    }
  } else if (blk <= 100) {
    int u0 = (blk - 76) * 8;
    __shared__ float wbs[8][200];
    for (int i = t; i < 8 * 200; i += 256)
      wbs[i / 200][i % 200] = Watt[(size_t)(u0 + i / 200) * 600 + 400 + i % 200];
    __syncthreads();
    if (t < 200) {
      int j = t;
      float acc[8] = {0, 0, 0, 0, 0, 0, 0, 0};
      for (int i = 0; i < 200; i += 4) {
        float r0v = W6[(size_t)i * 400 + 200 + j];
        float r1v = W6[(size_t)(i + 1) * 400 + 200 + j];
        float r2v = W6[(size_t)(i + 2) * 400 + 200 + j];
        float r3v = W6[(size_t)(i + 3) * 400 + 200 + j];
#pragma unroll
        for (int s = 0; s < 8; ++s)
          acc[s] += wbs[s][i] * r0v + wbs[s][i + 1] * r1v + wbs[s][i + 2] * r2v +
                    wbs[s][i + 3] * r3v;
      }
#pragma unroll
      for (int s = 0; s < 8; ++s) W6bb[(size_t)(u0 + s) * 200 + j] = acc[s];
    }
  } else {
    __shared__ float tlds[64][65];
    int tb = blk - 101;
    const float* src;
    float* dst;
    int M, N, LD, ti, tj;
    if (tb < 28) {
      src = rel_emb; dst = relT; M = 400; N = 200; LD = 200;
      ti = tb / 4; tj = tb % 4;
    } else if (tb < 56) {
      tb -= 28;
      src = Watt; dst = WaT; M = 200; N = 400; LD = 600;
      ti = tb / 7; tj = tb % 7;
    } else if (tb < 147) {
      tb -= 56;
      src = W1; dst = W1T; M = 400; N = 800; LD = 800;
      ti = tb / 13; tj = tb % 13;
    } else {
      tb -= 147;
      src = W2; dst = W2T; M = 400; N = 400; LD = 400;
      ti = tb / 7; tj = tb % 7;
    }
    int i0 = ti * 64, j0 = tj * 64;
    for (int idx = t; idx < 4096; idx += 256) {
      int r = idx >> 6, c = idx & 63;
      int i = i0 + r, j = j0 + c;
      if (i < M && j < N) tlds[r][c] = src[(size_t)i * LD + j];
    }
    __syncthreads();
    for (int idx = t; idx < 4096; idx += 256) {
      int r = idx >> 6, c = idx & 63;
      int j = j0 + r, i = i0 + c;
      if (i < M && j < N) dst[(size_t)j * M + i] = tlds[c][r];
    }
  }
}

// ---------------------------------------------------------------------------
// prep2_x1: blocks 0..125 do prep2 (S_T,cvec,Q_T,REatt,v1);
//           blocks 126..381 do x1 (2 rows each). 1024 threads.
// ---------------------------------------------------------------------------
__global__ __launch_bounds__(1024) void prep2_x1_kernel(
    const float* __restrict__ rel_emb, const float* __restrict__ W3,
    const float* __restrict__ b3, const float* __restrict__ W6,
    const float* __restrict__ Watt, const float* __restrict__ batt,
    const float* __restrict__ b6, const float* __restrict__ RK,
    const float* __restrict__ P, const float* __restrict__ W6bb,
    const float* __restrict__ ab, float* __restrict__ S_T,
    float* __restrict__ cvec, float* __restrict__ Q_T,
    float* __restrict__ REatt, float* __restrict__ v1,
    const float* __restrict__ ent_emb, const float* __restrict__ H,
    const int* __restrict__ e_idx, const int* __restrict__ q_idx,
    const float* __restrict__ W1T, const float* __restrict__ b1,
    float* __restrict__ X) {
  int t = threadIdx.x;
  int blk = blockIdx.x;
  if (blk < 50) {
    int r0 = blk * 8;
    __shared__ float rks[8][200];
    __shared__ float b3s[200];
    for (int i = t; i < 1600; i += 1024)
      rks[i / 200][i % 200] = RK[(size_t)r0 * 200 + i];
    if (t < 200) b3s[t] = b3[t];
    __syncthreads();
    if (t < 200) {
      int i = t;
      float acc[8] = {0, 0, 0, 0, 0, 0, 0, 0};
      for (int j = 0; j < 200; j += 4) {
        float w0 = W3[(size_t)j * 200 + i];
        float w1 = W3[(size_t)(j + 1) * 200 + i];
        float w2 = W3[(size_t)(j + 2) * 200 + i];
        float w3v = W3[(size_t)(j + 3) * 200 + i];
#pragma unroll
        for (int s = 0; s < 8; ++s)
          acc[s] += w0 * rks[s][j] + w1 * rks[s][j + 1] + w2 * rks[s][j + 2] +
                    w3v * rks[s][j + 3];
      }
      float4 s0 = make_float4(acc[0], acc[1], acc[2], acc[3]);
      float4 s1 = make_float4(acc[4], acc[5], acc[6], acc[7]);
      *(float4*)(S_T + (size_t)i * 400 + r0) = s0;
      *(float4*)(S_T + (size_t)i * 400 + r0 + 4) = s1;
    }
    if (t < 256) {
      int w = t >> 6, lane = t & 63;
      float p0 = 0.f, p1 = 0.f;
      for (int j = lane; j < 200; j += 64) {
        p0 += b3s[j] * rks[w][j];
        p1 += b3s[j] * rks[w + 4][j];
      }
      p0 = wave_rsum(p0);
      p1 = wave_rsum(p1);
      if (lane == 0) {
        cvec[r0 + w] = p0;
        cvec[r0 + w + 4] = p1;
      }
    }
  } else if (blk < 75) {
    int u0 = (blk - 50) * 8;
    __shared__ float wbs[8][200];
    for (int i = t; i < 1600; i += 1024)
      wbs[i / 200][i % 200] = Watt[(size_t)(u0 + i / 200) * 600 + 400 + i % 200];
    __syncthreads();
    if (t < 200) {
      int k = t;
      float acc[8] = {0, 0, 0, 0, 0, 0, 0, 0};
      for (int i = 0; i < 200; i += 4) {
        float r0v = P[(size_t)i * 200 + k];
        float r1v = P[(size_t)(i + 1) * 200 + k];
        float r2v = P[(size_t)(i + 2) * 200 + k];
        float r3v = P[(size_t)(i + 3) * 200 + k];
#pragma unroll
        for (int s = 0; s < 8; ++s)
          acc[s] += wbs[s][i] * r0v + wbs[s][i + 1] * r1v + wbs[s][i + 2] * r2v +
                    wbs[s][i + 3] * r3v;
      }
      float4 s0 = make_float4(acc[0], acc[1], acc[2], acc[3]);
      float4 s1 = make_float4(acc[4], acc[5], acc[6], acc[7]);
      *(float4*)(Q_T + (size_t)k * 200 + u0) = s0;
      *(float4*)(Q_T + (size_t)k * 200 + u0 + 4) = s1;
    }
  } else if (blk < 125) {
    int r0 = (blk - 75) * 8;
    __shared__ float rels[8][200];
    for (int i = t; i < 1600; i += 1024)
      rels[i / 200][i % 200] = rel_emb[(size_t)r0 * 200 + i];
    __syncthreads();
    if (t < 200) {
      float acc[8] = {0, 0, 0, 0, 0, 0, 0, 0};
      const float4* w = (const float4*)(W6bb + (size_t)t * 200);
      for (int k = 0; k < 50; ++k) {
        float4 wv = w[k];
#pragma unroll
        for (int s = 0; s < 8; ++s) acc[s] += dot4(wv, ((const float4*)rels[s])[k]);
      }
#pragma unroll
      for (int s = 0; s < 8; ++s) REatt[(size_t)(r0 + s) * 200 + t] = acc[s];
    }
  } else if (blk == 125) {
    __shared__ float abs_[200];
    __shared__ float us[200];
    if (t < 200) abs_[t] = ab[t];
    __syncthreads();
    if (t < 200) {
      float u = b6[t];
      const float4* w = (const float4*)(W6 + (size_t)t * 400);
      const float4* rv = (const float4*)abs_;
      for (int k = 0; k < 50; ++k) u += dot4(w[k], rv[k]);
      us[t] = u;
    }
    __syncthreads();
    if (t < 200) {
      float v = batt[t];
      const float4* w = (const float4*)(Watt + (size_t)t * 600 + 400);
      const float4* rv = (const float4*)us;
      for (int k = 0; k < 50; ++k) v += dot4(w[k], rv[k]);
      v1[t] = v;
    }
  } else {
    // ----- x1 role: rows b0, b0+1 -----
    int b0 = (blk - 126) * 2;
    __shared__ float cv[2][800];
    __shared__ float prt[2][2][400];
    for (int i = t; i < 1600; i += 1024) {
      int s = i / 800, k = i % 800;
      float v;
      if (k < ENTd)
        v = ent_emb[(size_t)e_idx[b0 + s] * ENTd + k];
      else if (k < ENTd + HISTd)
        v = H[(size_t)(b0 + s) * HISTd + (k - ENTd)];
      else
        v = rel_emb[(size_t)q_idx[b0 + s] * RELd + (k - ENTd - HISTd)];
      cv[s][k] = v;
    }
    __syncthreads();
    if (t < 800) {
      int j = t % 400, h = t / 400;
      float a0 = 0.f, a1 = 0.f;
      const float* wp = W1T + j;
      int k0 = h * 400;
#pragma unroll 4
      for (int k = k0; k < k0 + 400; ++k) {
        float w0 = wp[(size_t)k * 400];
        a0 += w0 * cv[0][k];
        a1 += w0 * cv[1][k];
      }
      prt[h][0][j] = a0;
      prt[h][1][j] = a1;
    }
    __syncthreads();
    if (t < 800) {
      int s = t / 400, j = t % 400;
      X[(size_t)(b0 + s) * ADIMd + j] =
          fmaxf(b1[j] + prt[0][s][j] + prt[1][s][j], 0.f);
    }
  }
}

// ---------------------------------------------------------------------------
// x2rx: X2 = W2T^T . X + b2 ; RX[b][r] = rel_emb[r] . X2[b][:200]
// 1024 threads, R=2, grid 256  (unchanged)
// ---------------------------------------------------------------------------
__global__ __launch_bounds__(1024) void x2rx_kernel(
    const float* __restrict__ X, const float* __restrict__ W2T,
    const float* __restrict__ b2, const float* __restrict__ relT,
    float* __restrict__ X2, float* __restrict__ RX) {
  int b0 = blockIdx.x * 2;
  int t = threadIdx.x;
  __shared__ float cv[2][400];
  __shared__ float prt[2][2][400];
  __shared__ float x2lo[2][200];
  for (int i = t; i < 800; i += 1024) cv[i / 400][i % 400] = X[(size_t)b0 * 400 + i];
  __syncthreads();
  if (t < 800) {
    int j = t % 400, h = t / 400;
    float a0 = 0.f, a1 = 0.f;
    const float* wp = W2T + j;
    int k0 = h * 200;
#pragma unroll 4
    for (int k = k0; k < k0 + 200; ++k) {
      float w0 = wp[(size_t)k * 400];
      a0 += w0 * cv[0][k];
      a1 += w0 * cv[1][k];
    }
    prt[h][0][j] = a0;
    prt[h][1][j] = a1;
  }
  __syncthreads();
  if (t < 800) {
    int s = t / 400, j = t % 400;
    float v = b2[j] + prt[0][s][j] + prt[1][s][j];
    X2[(size_t)(b0 + s) * ADIMd + j] = v;
    if (j < 200) x2lo[s][j] = v;
  }
  __syncthreads();
  if (t < 800) {
    int r = t % 400, h = t / 400;
    const float* rp = relT + r;
    float a0 = 0.f, a1 = 0.f;
    int k0 = h * 100;
#pragma unroll 4
    for (int k = k0; k < k0 + 100; ++k) {
      float w0 = rp[(size_t)k * 400];
      a0 += w0 * x2lo[0][k];
      a1 += w0 * x2lo[1][k];
    }
    prt[h][0][r] = a0;
    prt[h][1][r] = a1;
  }
  __syncthreads();
  if (t < 800) {
    int s = t / 400, r = t % 400;
    RX[(size_t)(b0 + s) * NRr + r] = prt[0][s][r] + prt[1][s][r];
  }
}

// ---------------------------------------------------------------------------
// tail: blocks 0..255 = fused_mid (R=2); blocks 256..767 = scores (1 row).
// 1024 threads. fused (L2/VALU-bound) and scores (gather-latency-bound)
// co-resident so their resource usage overlaps.
// ---------------------------------------------------------------------------
__global__ __launch_bounds__(1024) void tail_kernel(
    const float* __restrict__ ent_emb, const int* __restrict__ pred_id,
    const float* __restrict__ X2, const float* __restrict__ S_T,
    const float* __restrict__ cvec, const float* __restrict__ Q_T,
    const float* __restrict__ REatt, const float* __restrict__ relT,
    const float* __restrict__ WaT, const float* __restrict__ v1c,
    const float* __restrict__ RX, const int* __restrict__ r_space,
    const int* __restrict__ e_space, const float* __restrict__ mask,
    float* __restrict__ out_ratt, float* __restrict__ out_dist,
    float* __restrict__ out_ent) {
  int t = threadIdx.x;
  int w = t >> 6, lane = t & 63;
  // fused role shared
  __shared__ float pes[2][200];
  __shared__ float x2s[2][400];
  __shared__ float pp[2][400];
  __shared__ float av[2][200];
  __shared__ float prt[1600];
  __shared__ float wred[2][8];
  // scores role shared
  __shared__ float x2hi[200];
  __shared__ float scl[256];
  __shared__ float wr[4];

  if (blockIdx.x < 256) {
    int b0 = blockIdx.x * 2;
    // pes (400) + x2s (800) = 1200 elements, strided load (BUG FIXED)
    for (int i = t; i < 1200; i += 1024) {
      if (i < 400)
        pes[i / 200][i % 200] =
            ent_emb[(size_t)pred_id[b0 + i / 200] * ENTd + i % 200];
      else {
        int k = i - 400;
        x2s[k / 400][k % 400] = X2[(size_t)b0 * 400 + k];
      }
    }
    __syncthreads();
    // --- la: 2-way k-split ---
    if (t < 800) {
      int r = t % 400, h = t / 400;
      float a0 = 0.f, a1 = 0.f;
      const float* sp = S_T + r;
      int k0 = h * 100;
#pragma unroll 4
      for (int k = k0; k < k0 + 100; ++k) {
        float w0 = sp[(size_t)k * 400];
        a0 += w0 * pes[0][k];
        a1 += w0 * pes[1][k];
      }
      prt[(h * 2 + 0) * 400 + r] = a0;
      prt[(h * 2 + 1) * 400 + r] = a1;
    }
    __syncthreads();
    if (t < 800) {
      int s = t / 400, r = t % 400;
      pp[s][r] = cvec[r] + prt[(0 * 2 + s) * 400 + r] + prt[(1 * 2 + s) * 400 + r];
    }
    __syncthreads();
    int row = w >> 3, q = w & 7;  // 8 waves per batch row
    // --- softmax(pp rows) ---
    {
      int r = q * 64 + lane;
      float m = (r < 400) ? pp[row][r] : -INFINITY;
      m = wave_rmax(m);
      if (lane == 0) wred[row][q] = m;
      __syncthreads();
      float gm = wred[row][0];
#pragma unroll
      for (int i = 1; i < 8; ++i) gm = fmaxf(gm, wred[row][i]);
      __syncthreads();
      float e = 0.f;
      if (r < 400) {
        e = expf(pp[row][r] - gm);
        pp[row][r] = e;
      }
      float sum = wave_rsum(e);
      if (lane == 0) wred[row][q] = sum;
      __syncthreads();
      float gs = 0.f;
#pragma unroll
      for (int i = 0; i < 8; ++i) gs += wred[row][i];
      float inv = 1.f / gs;
      if (r < 400) pp[row][r] *= inv;
    }
    __syncthreads();
    // --- attv: 4-way k-split ---
    if (t < 800) {
      int j = t % 200, h = t / 200;
      float a0, a1;
      if (h == 0) {
        float v = v1c[j];
        a0 = v; a1 = v;
      } else {
        a0 = 0.f; a1 = 0.f;
      }
      {
        const float* wp = WaT + (size_t)(h * 100) * 200 + j;
        int kb = h * 100;
#pragma unroll 4
        for (int k = 0; k < 100; ++k) {
          float w0 = wp[(size_t)k * 200];
          a0 += w0 * x2s[0][kb + k];
          a1 += w0 * x2s[1][kb + k];
        }
      }
      {
        const float* qp = Q_T + (size_t)(h * 50) * 200 + j;
        int kb = h * 50;
#pragma unroll 4
        for (int k = 0; k < 50; ++k) {
          float w0 = qp[(size_t)k * 200];
          a0 += w0 * pes[0][kb + k];
          a1 += w0 * pes[1][kb + k];
        }
      }
      {
        const float* rp = REatt + (size_t)(h * 100) * 200 + j;
        int rb = h * 100;
#pragma unroll 4
        for (int r = 0; r < 100; ++r) {
          float w0 = rp[(size_t)r * 200];
          a0 += w0 * pp[0][rb + r];
          a1 += w0 * pp[1][rb + r];
        }
      }
      prt[(h * 2 + 0) * 200 + j] = a0;
      prt[(h * 2 + 1) * 200 + j] = a1;
    }
    __syncthreads();
    if (t < 400) {
      int s = t / 200, j = t % 200;
      av[s][j] = prt[(0 * 2 + s) * 200 + j] + prt[(1 * 2 + s) * 200 + j] +
                 prt[(2 * 2 + s) * 200 + j] + prt[(3 * 2 + s) * 200 + j];
    }
    __syncthreads();
    // --- logits: 2-way k-split ---
    if (t < 800) {
      int r = t % 400, h = t / 400;
      const float* rp = relT + r;
      float a0 = 0.f, a1 = 0.f;
      int k0 = h * 100;
#pragma unroll 4
      for (int k = k0; k < k0 + 100; ++k) {
        float w0 = rp[(size_t)k * 400];
        a0 += w0 * av[0][k];
        a1 += w0 * av[1][k];
      }
      prt[(h * 2 + 0) * 400 + r] = a0;
      prt[(h * 2 + 1) * 400 + r] = a1;
    }
    __syncthreads();
    if (t < 800) {
      int s = t / 400, r = t % 400;
      pp[s][r] = prt[(0 * 2 + s) * 400 + r] + prt[(1 * 2 + s) * 400 + r];
    }
    __syncthreads();
    // --- softmax + write ---
    {
      int r = q * 64 + lane;
      float m = (r < 400) ? pp[row][r] : -INFINITY;
      m = wave_rmax(m);
      if (lane == 0) wred[row][q] = m;
      __syncthreads();
      float gm = wred[row][0];
#pragma unroll
      for (int i = 1; i < 8; ++i) gm = fmaxf(gm, wred[row][i]);
      __syncthreads();
      float e = 0.f;
      if (r < 400) e = expf(pp[row][r] - gm);
      float sum = wave_rsum(e);
      if (lane == 0) wred[row][q] = sum;
      __syncthreads();
      float gs = 0.f;
#pragma unroll
      for (int i = 0; i < 8; ++i) gs += wred[row][i];
      float inv = 1.f / gs;
      if (r < 400) out_ratt[(size_t)(b0 + row) * 400 + r] = e * inv;
    }
  } else {
    // ---------------- scores role: one batch row ----------------
    int b = blockIdx.x - 256;
    if (t >= 200 && t < 400) x2hi[t - 200] = X2[(size_t)b * ADIMd + t];
    __syncthreads();
    const float4* xh = (const float4*)x2hi;
    // 16 waves x 16 actions each, 8 gathers in flight
    for (int c = 0; c < 2; ++c) {
      int abase = w * 16 + c * 8;
      int ei[8];
#pragma unroll
      for (int u = 0; u < 8; ++u) ei[u] = e_space[(size_t)b * AA + abase + u];
      float p[8];
      if (lane < 50) {
        float4 xv = xh[lane];
#pragma unroll
        for (int u = 0; u < 8; ++u) {
          float4 vv = ((const float4*)(ent_emb + (size_t)ei[u] * ENTd))[lane];
          p[u] = dot4(vv, xv);
        }
      } else {
#pragma unroll
        for (int u = 0; u < 8; ++u) p[u] = 0.f;
      }
#pragma unroll
      for (int off = 32; off > 0; off >>= 1) {
#pragma unroll
        for (int u = 0; u < 8; ++u) p[u] += __shfl_xor(p[u], off);
      }
      if (lane == 0) {
#pragma unroll
        for (int u = 0; u < 8; ++u) scl[abase + u] = p[u];
      }
    }
    __syncthreads();
    float sc = -INFINITY;
    if (t < 256) {
      int r = r_space[(size_t)b * AA + t];
      sc = scl[t] + RX[(size_t)b * NRr + r] -
           (1.f - mask[(size_t)b * AA + t]) * 1e31f;
    }
    __syncthreads();
    if (w < 4) {
      float m = wave_rmax(sc);
      if (lane == 0) wr[w] = m;
    }
    __syncthreads();
    float gm = fmaxf(fmaxf(wr[0], wr[1]), fmaxf(wr[2], wr[3]));
    float e = (t < 256) ? expf(sc - gm) : 0.f;
    __syncthreads();
    if (w < 4) {
      float s2 = wave_rsum(e);
      if (lane == 0) wr[w] = s2;
    }
    __syncthreads();
    float gs = wr[0] + wr[1] + wr[2] + wr[3];
    float p = e / gs;
    if (t < 256) out_dist[(size_t)b * AA + t] = p;
    float ent = (t < 256) ? -p * logf(p + 1e-20f) : 0.f;
    __syncthreads();
    if (w < 4) {
      float s3 = wave_rsum(ent);
      if (lane == 0) wr[w] = s3;
    }
    __syncthreads();
    if (t == 0) out_ent[b] = wr[0] + wr[1] + wr[2] + wr[3];
  }
}

// ---------------------------------------------------------------------------
extern "C" void kernel_launch(void* const* d_in, const int* in_sizes, int n_in,
                              void* d_out, int out_size, void* d_ws,
                              size_t ws_size, hipStream_t stream) {
  const float* H = (const float*)d_in[0];
  const float* mask = (const float*)d_in[1];
  const float* ent_emb = (const float*)d_in[2];
  const float* rel_emb = (const float*)d_in[3];
  const float* W1 = (const float*)d_in[4];
  const float* b1 = (const float*)d_in[5];
  const float* W2 = (const float*)d_in[6];
  const float* b2 = (const float*)d_in[7];
  const float* W3 = (const float*)d_in[8];
  const float* b3 = (const float*)d_in[9];
  const float* W4 = (const float*)d_in[10];
  const float* b4 = (const float*)d_in[11];
  const float* W5 = (const float*)d_in[12];
  const float* b5 = (const float*)d_in[13];
  const float* W6 = (const float*)d_in[14];
  const float* b6 = (const float*)d_in[15];
  const float* Watt = (const float*)d_in[16];
  const float* batt = (const float*)d_in[17];
  const int* e_idx = (const int*)d_in[18];
  const int* q_idx = (const int*)d_in[19];
  const int* pred_id = (const int*)d_in[20];
  const int* r_space = (const int*)d_in[21];
  const int* e_space = (const int*)d_in[22];

  float* ws = (float*)d_ws;
  float* RK = ws;                   // 80000
  float* S_T = ws + 80000;          // 80000  [200][400]
  float* cvec = ws + 160000;        // 512
  float* P = ws + 160512;           // 40000
  float* Q_T = ws + 200512;         // 40000  [200][200]
  float* W6bb = ws + 240512;        // 40000
  float* REatt = ws + 280512;       // 80000  [400][200]
  float* relT = ws + 360512;        // 80000  [200][400]
  float* WaT = ws + 440512;         // 80000  [400][200]
  float* W1T = ws + 520512;         // 320000 [800][400]
  float* W2T = ws + 840512;         // 160000 [400][400]
  float* ab = ws + 1000512;         // 256
  float* v1 = ws + 1000768;         // 256
  float* X = ws + 1001024;          // 204800
  float* X2 = ws + 1205824;         // 204800
  float* RX = ws + 1410624;         // 204800 [512][400]

  float* out = (float*)d_out;
  float* out_dist = out;                 // [512,256]
  float* out_ent = out + BB * AA;        // [512]
  float* out_ratt = out + BB * AA + BB;  // [512,400]

  hipLaunchKernelGGL(prep1_kernel, dim3(297), dim3(256), 0, stream, rel_emb,
                     W4, b4, W5, b5, W6, Watt, W1, W2, RK, P, W6bb, ab, relT,
                     WaT, W1T, W2T);
  hipLaunchKernelGGL(prep2_x1_kernel, dim3(382), dim3(1024), 0, stream,
                     rel_emb, W3, b3, W6, Watt, batt, b6, RK, P, W6bb, ab,
                     S_T, cvec, Q_T, REatt, v1, ent_emb, H, e_idx, q_idx,
                     W1T, b1, X);
  hipLaunchKernelGGL(x2rx_kernel, dim3(256), dim3(1024), 0, stream, X, W2T,
                     b2, relT, X2, RX);
  hipLaunchKernelGGL(tail_kernel, dim3(768), dim3(1024), 0, stream, ent_emb,
                     pred_id, X2, S_T, cvec, Q_T, REatt, relT, WaT, v1, RX,
                     r_space, e_space, mask, out_ratt, out_dist, out_ent);
}

// Round 11
// 101.884 us; speedup vs baseline: 2.4832x; 1.3387x over previous
//
#include <hip/hip_runtime.h>
#include <cstdint>
#include <cstddef>

#define BB 512
#define NEn 100000
#define NRr 400
#define AA 256
#define ENTd 200
#define RELd 200
#define HISTd 400
#define ADIMd 400

__device__ __forceinline__ float dot4(const float4 a, const float4 b) {
  return a.x * b.x + a.y * b.y + a.z * b.z + a.w * b.w;
}
__device__ __forceinline__ void fma4(float4& a, const float4 w, const float c) {
  a.x += w.x * c; a.y += w.y * c; a.z += w.z * c; a.w += w.w * c;
}
__device__ __forceinline__ float wave_rmax(float v) {
#pragma unroll
  for (int off = 32; off > 0; off >>= 1) v = fmaxf(v, __shfl_xor(v, off));
  return v;
}
__device__ __forceinline__ float wave_rsum(float v) {
#pragma unroll
  for (int off = 32; off > 0; off >>= 1) v += __shfl_xor(v, off);
  return v;
}

// ---------------------------------------------------------------------------
// prep1: RK, P, W6bb, ab + tiled transposes relT/WaT/W1T/W2T  (unchanged)
// ---------------------------------------------------------------------------
__global__ __launch_bounds__(256) void prep1_kernel(
    const float* __restrict__ rel_emb, const float* __restrict__ W4,
    const float* __restrict__ b4, const float* __restrict__ W5,
    const float* __restrict__ b5, const float* __restrict__ W6,
    const float* __restrict__ Watt, const float* __restrict__ W1,
    const float* __restrict__ W2, float* __restrict__ RK,
    float* __restrict__ P, float* __restrict__ W6bb, float* __restrict__ ab,
    float* __restrict__ relT, float* __restrict__ WaT,
    float* __restrict__ W1T, float* __restrict__ W2T) {
  int t = threadIdx.x;
  int blk = blockIdx.x;
  if (blk == 0) {
    __shared__ float rs[RELd];
    if (t < RELd) {
      float s = 0.f;
      for (int r = 0; r < NRr; r += 4) {
        s += rel_emb[(size_t)r * RELd + t] + rel_emb[(size_t)(r + 1) * RELd + t] +
             rel_emb[(size_t)(r + 2) * RELd + t] + rel_emb[(size_t)(r + 3) * RELd + t];
      }
      rs[t] = s;
    }
    __syncthreads();
    if (t < RELd) {
      float acc = b5[t];
      const float4* w = (const float4*)(W5 + (size_t)t * 400);
      const float4* rv = (const float4*)rs;
      for (int k = 0; k < 50; ++k) acc += dot4(w[k], rv[k]);
      ab[t] = acc;
    }
  } else if (blk <= 50) {
    int r0 = (blk - 1) * 8;
    __shared__ float re[8][RELd];
    for (int i = t; i < 8 * RELd; i += 256)
      re[i / RELd][i % RELd] = rel_emb[(size_t)(r0 + i / RELd) * RELd + i % RELd];
    __syncthreads();
    if (t < RELd) {
      float bv = b4[t];
      float acc[8];
#pragma unroll
      for (int s = 0; s < 8; ++s) acc[s] = bv;
      const float4* w = (const float4*)(W4 + (size_t)t * RELd);
      for (int k = 0; k < 50; ++k) {
        float4 wv = w[k];
#pragma unroll
        for (int s = 0; s < 8; ++s) acc[s] += dot4(wv, ((const float4*)re[s])[k]);
      }
#pragma unroll
      for (int s = 0; s < 8; ++s) RK[(size_t)(r0 + s) * RELd + t] = acc[s];
    }
  } else if (blk <= 75) {
    int i0 = (blk - 51) * 8;
    __shared__ float w6s[8][200];
    for (int i = t; i < 8 * 200; i += 256)
      w6s[i / 200][i % 200] = W6[(size_t)(i0 + i / 200) * 400 + i % 200];
    __syncthreads();
    if (t < 200) {
      int k = t;
      float acc[8] = {0, 0, 0, 0, 0, 0, 0, 0};
      for (int j = 0; j < 200; j += 4) {
        float r0v = W5[(size_t)j * 400 + 200 + k];
        float r1v = W5[(size_t)(j + 1) * 400 + 200 + k];
        float r2v = W5[(size_t)(j + 2) * 400 + 200 + k];
        float r3v = W5[(size_t)(j + 3) * 400 + 200 + k];
#pragma unroll
        for (int s = 0; s < 8; ++s)
          acc[s] += w6s[s][j] * r0v + w6s[s][j + 1] * r1v + w6s[s][j + 2] * r2v +
                    w6s[s][j + 3] * r3v;
      }
#pragma unroll
      for (int s = 0; s < 8; ++s) P[(size_t)(i0 + s) * 200 + k] = 400.f * acc[s];
    }
  } else if (blk <= 100) {
    int u0 = (blk - 76) * 8;
    __shared__ float wbs[8][200];
    for (int i = t; i < 8 * 200; i += 256)
      wbs[i / 200][i % 200] = Watt[(size_t)(u0 + i / 200) * 600 + 400 + i % 200];
    __syncthreads();
    if (t < 200) {
      int j = t;
      float acc[8] = {0, 0, 0, 0, 0, 0, 0, 0};
      for (int i = 0; i < 200; i += 4) {
        float r0v = W6[(size_t)i * 400 + 200 + j];
        float r1v = W6[(size_t)(i + 1) * 400 + 200 + j];
        float r2v = W6[(size_t)(i + 2) * 400 + 200 + j];
        float r3v = W6[(size_t)(i + 3) * 400 + 200 + j];
#pragma unroll
        for (int s = 0; s < 8; ++s)
          acc[s] += wbs[s][i] * r0v + wbs[s][i + 1] * r1v + wbs[s][i + 2] * r2v +
                    wbs[s][i + 3] * r3v;
      }
#pragma unroll
      for (int s = 0; s < 8; ++s) W6bb[(size_t)(u0 + s) * 200 + j] = acc[s];
    }
  } else {
    __shared__ float tlds[64][65];
    int tb = blk - 101;
    const float* src;
    float* dst;
    int M, N, LD, ti, tj;
    if (tb < 28) {
      src = rel_emb; dst = relT; M = 400; N = 200; LD = 200;
      ti = tb / 4; tj = tb % 4;
    } else if (tb < 56) {
      tb -= 28;
      src = Watt; dst = WaT; M = 200; N = 400; LD = 600;
      ti = tb / 7; tj = tb % 7;
    } else if (tb < 147) {
      tb -= 56;
      src = W1; dst = W1T; M = 400; N = 800; LD = 800;
      ti = tb / 13; tj = tb % 13;
    } else {
      tb -= 147;
      src = W2; dst = W2T; M = 400; N = 400; LD = 400;
      ti = tb / 7; tj = tb % 7;
    }
    int i0 = ti * 64, j0 = tj * 64;
    for (int idx = t; idx < 4096; idx += 256) {
      int r = idx >> 6, c = idx & 63;
      int i = i0 + r, j = j0 + c;
      if (i < M && j < N) tlds[r][c] = src[(size_t)i * LD + j];
    }
    __syncthreads();
    for (int idx = t; idx < 4096; idx += 256) {
      int r = idx >> 6, c = idx & 63;
      int j = j0 + r, i = i0 + c;
      if (i < M && j < N) dst[(size_t)j * M + i] = tlds[c][r];
    }
  }
}

// ---------------------------------------------------------------------------
// prep2_x1: blocks 0..125 = prep2 roles; blocks 126..381 = x1 (2 rows, f4)
// ---------------------------------------------------------------------------
__global__ __launch_bounds__(1024) void prep2_x1_kernel(
    const float* __restrict__ rel_emb, const float* __restrict__ W3,
    const float* __restrict__ b3, const float* __restrict__ W6,
    const float* __restrict__ Watt, const float* __restrict__ batt,
    const float* __restrict__ b6, const float* __restrict__ RK,
    const float* __restrict__ P, const float* __restrict__ W6bb,
    const float* __restrict__ ab, float* __restrict__ S_T,
    float* __restrict__ cvec, float* __restrict__ Q_T,
    float* __restrict__ REatt, float* __restrict__ v1,
    const float* __restrict__ ent_emb, const float* __restrict__ H,
    const int* __restrict__ e_idx, const int* __restrict__ q_idx,
    const float* __restrict__ W1T, const float* __restrict__ b1,
    float* __restrict__ X) {
  int t = threadIdx.x;
  int blk = blockIdx.x;
  if (blk < 50) {
    int r0 = blk * 8;
    __shared__ float rks[8][200];
    __shared__ float b3s[200];
    for (int i = t; i < 1600; i += 1024)
      rks[i / 200][i % 200] = RK[(size_t)r0 * 200 + i];
    if (t < 200) b3s[t] = b3[t];
    __syncthreads();
    if (t < 200) {
      int i = t;
      float acc[8] = {0, 0, 0, 0, 0, 0, 0, 0};
      for (int j = 0; j < 200; j += 4) {
        float w0 = W3[(size_t)j * 200 + i];
        float w1 = W3[(size_t)(j + 1) * 200 + i];
        float w2 = W3[(size_t)(j + 2) * 200 + i];
        float w3v = W3[(size_t)(j + 3) * 200 + i];
#pragma unroll
        for (int s = 0; s < 8; ++s)
          acc[s] += w0 * rks[s][j] + w1 * rks[s][j + 1] + w2 * rks[s][j + 2] +
                    w3v * rks[s][j + 3];
      }
      float4 s0 = make_float4(acc[0], acc[1], acc[2], acc[3]);
      float4 s1 = make_float4(acc[4], acc[5], acc[6], acc[7]);
      *(float4*)(S_T + (size_t)i * 400 + r0) = s0;
      *(float4*)(S_T + (size_t)i * 400 + r0 + 4) = s1;
    }
    if (t < 256) {
      int w = t >> 6, lane = t & 63;
      float p0 = 0.f, p1 = 0.f;
      for (int j = lane; j < 200; j += 64) {
        p0 += b3s[j] * rks[w][j];
        p1 += b3s[j] * rks[w + 4][j];
      }
      p0 = wave_rsum(p0);
      p1 = wave_rsum(p1);
      if (lane == 0) {
        cvec[r0 + w] = p0;
        cvec[r0 + w + 4] = p1;
      }
    }
  } else if (blk < 75) {
    int u0 = (blk - 50) * 8;
    __shared__ float wbs[8][200];
    for (int i = t; i < 1600; i += 1024)
      wbs[i / 200][i % 200] = Watt[(size_t)(u0 + i / 200) * 600 + 400 + i % 200];
    __syncthreads();
    if (t < 200) {
      int k = t;
      float acc[8] = {0, 0, 0, 0, 0, 0, 0, 0};
      for (int i = 0; i < 200; i += 4) {
        float r0v = P[(size_t)i * 200 + k];
        float r1v = P[(size_t)(i + 1) * 200 + k];
        float r2v = P[(size_t)(i + 2) * 200 + k];
        float r3v = P[(size_t)(i + 3) * 200 + k];
#pragma unroll
        for (int s = 0; s < 8; ++s)
          acc[s] += wbs[s][i] * r0v + wbs[s][i + 1] * r1v + wbs[s][i + 2] * r2v +
                    wbs[s][i + 3] * r3v;
      }
      float4 s0 = make_float4(acc[0], acc[1], acc[2], acc[3]);
      float4 s1 = make_float4(acc[4], acc[5], acc[6], acc[7]);
      *(float4*)(Q_T + (size_t)k * 200 + u0) = s0;
      *(float4*)(Q_T + (size_t)k * 200 + u0 + 4) = s1;
    }
  } else if (blk < 125) {
    int r0 = (blk - 75) * 8;
    __shared__ float rels[8][200];
    for (int i = t; i < 1600; i += 1024)
      rels[i / 200][i % 200] = rel_emb[(size_t)r0 * 200 + i];
    __syncthreads();
    if (t < 200) {
      float acc[8] = {0, 0, 0, 0, 0, 0, 0, 0};
      const float4* w = (const float4*)(W6bb + (size_t)t * 200);
      for (int k = 0; k < 50; ++k) {
        float4 wv = w[k];
#pragma unroll
        for (int s = 0; s < 8; ++s) acc[s] += dot4(wv, ((const float4*)rels[s])[k]);
      }
#pragma unroll
      for (int s = 0; s < 8; ++s) REatt[(size_t)(r0 + s) * 200 + t] = acc[s];
    }
  } else if (blk == 125) {
    __shared__ float abs_[200];
    __shared__ float us[200];
    if (t < 200) abs_[t] = ab[t];
    __syncthreads();
    if (t < 200) {
      float u = b6[t];
      const float4* w = (const float4*)(W6 + (size_t)t * 400);
      const float4* rv = (const float4*)abs_;
      for (int k = 0; k < 50; ++k) u += dot4(w[k], rv[k]);
      us[t] = u;
    }
    __syncthreads();
    if (t < 200) {
      float v = batt[t];
      const float4* w = (const float4*)(Watt + (size_t)t * 600 + 400);
      const float4* rv = (const float4*)us;
      for (int k = 0; k < 50; ++k) v += dot4(w[k], rv[k]);
      v1[t] = v;
    }
  } else {
    // ----- x1 role (f4): rows b0, b0+1; thread owns 4 j's, 8-way k-split ---
    int b0 = (blk - 126) * 2;
    __shared__ float cv[2][800];
    __shared__ float prt[6400];  // [h][s][j] as [(h*2+s)*400 + j]
    for (int i = t; i < 1600; i += 1024) {
      int s = i / 800, k = i % 800;
      float v;
      if (k < ENTd)
        v = ent_emb[(size_t)e_idx[b0 + s] * ENTd + k];
      else if (k < ENTd + HISTd)
        v = H[(size_t)(b0 + s) * HISTd + (k - ENTd)];
      else
        v = rel_emb[(size_t)q_idx[b0 + s] * RELd + (k - ENTd - HISTd)];
      cv[s][k] = v;
    }
    __syncthreads();
    if (t < 800) {
      int g = t % 100, h = t / 100;  // h in [0,8), k-chunk 100
      float4 accA = make_float4(0, 0, 0, 0);
      float4 accB = make_float4(0, 0, 0, 0);
      const float4* wp = ((const float4*)W1T) + g;  // W1T[k][4g]
      int k0 = h * 100;
#pragma unroll 4
      for (int kk = 0; kk < 100; ++kk) {
        int k = k0 + kk;
        float4 wv = wp[(size_t)k * 100];
        fma4(accA, wv, cv[0][k]);
        fma4(accB, wv, cv[1][k]);
      }
      ((float4*)prt)[(h * 2 + 0) * 100 + g] = accA;
      ((float4*)prt)[(h * 2 + 1) * 100 + g] = accB;
    }
    __syncthreads();
    if (t < 800) {
      int s = t / 400, j = t % 400;
      float a = b1[j];
#pragma unroll
      for (int h = 0; h < 8; ++h) a += prt[(h * 2 + s) * 400 + j];
      X[(size_t)(b0 + s) * ADIMd + j] = fmaxf(a, 0.f);
    }
  }
}

// ---------------------------------------------------------------------------
// x2rx (f4): X2 = W2T^T.X + b2 ; RX = relT^T-dot. 1024 thr, R=2, grid 256
// ---------------------------------------------------------------------------
__global__ __launch_bounds__(1024) void x2rx_kernel(
    const float* __restrict__ X, const float* __restrict__ W2T,
    const float* __restrict__ b2, const float* __restrict__ relT,
    float* __restrict__ X2, float* __restrict__ RX) {
  int b0 = blockIdx.x * 2;
  int t = threadIdx.x;
  __shared__ float cv[2][400];
  __shared__ float prt[6400];
  __shared__ float x2lo[2][200];
  for (int i = t; i < 800; i += 1024) cv[i / 400][i % 400] = X[(size_t)b0 * 400 + i];
  __syncthreads();
  if (t < 800) {
    int g = t % 100, h = t / 100;  // h in [0,8), k-chunk 50
    float4 accA = make_float4(0, 0, 0, 0);
    float4 accB = make_float4(0, 0, 0, 0);
    const float4* wp = ((const float4*)W2T) + g;
    int k0 = h * 50;
#pragma unroll 4
    for (int kk = 0; kk < 50; ++kk) {
      int k = k0 + kk;
      float4 wv = wp[(size_t)k * 100];
      fma4(accA, wv, cv[0][k]);
      fma4(accB, wv, cv[1][k]);
    }
    ((float4*)prt)[(h * 2 + 0) * 100 + g] = accA;
    ((float4*)prt)[(h * 2 + 1) * 100 + g] = accB;
  }
  __syncthreads();
  if (t < 800) {
    int s = t / 400, j = t % 400;
    float a = b2[j];
#pragma unroll
    for (int h = 0; h < 8; ++h) a += prt[(h * 2 + s) * 400 + j];
    X2[(size_t)(b0 + s) * ADIMd + j] = a;
    if (j < 200) x2lo[s][j] = a;
  }
  __syncthreads();
  if (t < 800) {
    int g = t % 100, h = t / 100;  // h in [0,8), k-chunk 25
    float4 accA = make_float4(0, 0, 0, 0);
    float4 accB = make_float4(0, 0, 0, 0);
    const float4* rp = ((const float4*)relT) + g;
    int k0 = h * 25;
#pragma unroll 4
    for (int kk = 0; kk < 25; ++kk) {
      int k = k0 + kk;
      float4 wv = rp[(size_t)k * 100];
      fma4(accA, wv, x2lo[0][k]);
      fma4(accB, wv, x2lo[1][k]);
    }
    ((float4*)prt)[(h * 2 + 0) * 100 + g] = accA;
    ((float4*)prt)[(h * 2 + 1) * 100 + g] = accB;
  }
  __syncthreads();
  if (t < 800) {
    int s = t / 400, r = t % 400;
    float a = 0.f;
#pragma unroll
    for (int h = 0; h < 8; ++h) a += prt[(h * 2 + s) * 400 + r];
    RX[(size_t)(b0 + s) * NRr + r] = a;
  }
}

// ---------------------------------------------------------------------------
// tail: blocks 0..255 = fused_mid (R=2, f4 phases); 256..767 = scores.
// ---------------------------------------------------------------------------
__global__ __launch_bounds__(1024) void tail_kernel(
    const float* __restrict__ ent_emb, const int* __restrict__ pred_id,
    const float* __restrict__ X2, const float* __restrict__ S_T,
    const float* __restrict__ cvec, const float* __restrict__ Q_T,
    const float* __restrict__ REatt, const float* __restrict__ relT,
    const float* __restrict__ WaT, const float* __restrict__ v1c,
    const float* __restrict__ RX, const int* __restrict__ r_space,
    const int* __restrict__ e_space, const float* __restrict__ mask,
    float* __restrict__ out_ratt, float* __restrict__ out_dist,
    float* __restrict__ out_ent) {
  int t = threadIdx.x;
  int w = t >> 6, lane = t & 63;
  // fused role shared
  __shared__ float pes[2][200];
  __shared__ float x2s[2][400];
  __shared__ float pp[2][400];
  __shared__ float av[2][200];
  __shared__ float prt[6400];
  __shared__ float wred[2][8];
  // scores role shared
  __shared__ float x2hi[200];
  __shared__ float scl[256];
  __shared__ float wr[4];

  if (blockIdx.x < 256) {
    int b0 = blockIdx.x * 2;
    for (int i = t; i < 1200; i += 1024) {
      if (i < 400)
        pes[i / 200][i % 200] =
            ent_emb[(size_t)pred_id[b0 + i / 200] * ENTd + i % 200];
      else {
        int k = i - 400;
        x2s[k / 400][k % 400] = X2[(size_t)b0 * 400 + k];
      }
    }
    __syncthreads();
    // --- la (f4): thread owns 4 r's, 8-way k-split (chunk 25) ---
    if (t < 800) {
      int g = t % 100, h = t / 100;
      float4 accA = make_float4(0, 0, 0, 0);
      float4 accB = make_float4(0, 0, 0, 0);
      const float4* sp = ((const float4*)S_T) + g;
      int k0 = h * 25;
#pragma unroll 5
      for (int kk = 0; kk < 25; ++kk) {
        int k = k0 + kk;
        float4 wv = sp[(size_t)k * 100];
        fma4(accA, wv, pes[0][k]);
        fma4(accB, wv, pes[1][k]);
      }
      ((float4*)prt)[(h * 2 + 0) * 100 + g] = accA;
      ((float4*)prt)[(h * 2 + 1) * 100 + g] = accB;
    }
    __syncthreads();
    if (t < 800) {
      int s = t / 400, r = t % 400;
      float a = cvec[r];
#pragma unroll
      for (int h = 0; h < 8; ++h) a += prt[(h * 2 + s) * 400 + r];
      pp[s][r] = a;
    }
    __syncthreads();
    int row = w >> 3, q = w & 7;  // 8 waves per batch row
    // --- softmax(pp rows) ---
    {
      int r = q * 64 + lane;
      float m = (r < 400) ? pp[row][r] : -INFINITY;
      m = wave_rmax(m);
      if (lane == 0) wred[row][q] = m;
      __syncthreads();
      float gm = wred[row][0];
#pragma unroll
      for (int i = 1; i < 8; ++i) gm = fmaxf(gm, wred[row][i]);
      __syncthreads();
      float e = 0.f;
      if (r < 400) {
        e = expf(pp[row][r] - gm);
        pp[row][r] = e;
      }
      float sum = wave_rsum(e);
      if (lane == 0) wred[row][q] = sum;
      __syncthreads();
      float gs = 0.f;
#pragma unroll
      for (int i = 0; i < 8; ++i) gs += wred[row][i];
      float inv = 1.f / gs;
      if (r < 400) pp[row][r] *= inv;
    }
    __syncthreads();
    // --- attv (f4): thread owns 4 j's, 16-way split (chunk 25) ---
    if (t < 800) {
      int g = t % 50, h = t / 50;  // h in [0,16)
      float4 accA, accB;
      if (h == 0) {
        accA = ((const float4*)v1c)[g];
        accB = accA;
      } else {
        accA = make_float4(0, 0, 0, 0);
        accB = make_float4(0, 0, 0, 0);
      }
      {  // WaT [400][200], k-chunk 25
        const float4* wp = ((const float4*)WaT) + g;
        int k0 = h * 25;
#pragma unroll 5
        for (int kk = 0; kk < 25; ++kk) {
          int k = k0 + kk;
          float4 wv = wp[(size_t)k * 50];
          fma4(accA, wv, x2s[0][k]);
          fma4(accB, wv, x2s[1][k]);
        }
      }
      if (h < 8) {  // Q_T [200][200], k-chunk 25
        const float4* qp = ((const float4*)Q_T) + g;
        int k0 = h * 25;
#pragma unroll 5
        for (int kk = 0; kk < 25; ++kk) {
          int k = k0 + kk;
          float4 wv = qp[(size_t)k * 50];
          fma4(accA, wv, pes[0][k]);
          fma4(accB, wv, pes[1][k]);
        }
      }
      {  // REatt [400][200], r-chunk 25
        const float4* rp = ((const float4*)REatt) + g;
        int r0 = h * 25;
#pragma unroll 5
        for (int kk = 0; kk < 25; ++kk) {
          int r = r0 + kk;
          float4 wv = rp[(size_t)r * 50];
          fma4(accA, wv, pp[0][r]);
          fma4(accB, wv, pp[1][r]);
        }
      }
      ((float4*)prt)[(h * 2 + 0) * 50 + g] = accA;
      ((float4*)prt)[(h * 2 + 1) * 50 + g] = accB;
    }
    __syncthreads();
    if (t < 400) {
      int s = t / 200, j = t % 200;
      float a = 0.f;
#pragma unroll
      for (int h = 0; h < 16; ++h) a += prt[(h * 2 + s) * 200 + j];
      av[s][j] = a;
    }
    __syncthreads();
    // --- logits (f4): relT [200][400], thread owns 4 r's, 8-way (chunk 25) ---
    if (t < 800) {
      int g = t % 100, h = t / 100;
      float4 accA = make_float4(0, 0, 0, 0);
      float4 accB = make_float4(0, 0, 0, 0);
      const float4* rp = ((const float4*)relT) + g;
      int k0 = h * 25;
#pragma unroll 5
      for (int kk = 0; kk < 25; ++kk) {
        int k = k0 + kk;
        float4 wv = rp[(size_t)k * 100];
        fma4(accA, wv, av[0][k]);
        fma4(accB, wv, av[1][k]);
      }
      ((float4*)prt)[(h * 2 + 0) * 100 + g] = accA;
      ((float4*)prt)[(h * 2 + 1) * 100 + g] = accB;
    }
    __syncthreads();
    if (t < 800) {
      int s = t / 400, r = t % 400;
      float a = 0.f;
#pragma unroll
      for (int h = 0; h < 8; ++h) a += prt[(h * 2 + s) * 400 + r];
      pp[s][r] = a;
    }
    __syncthreads();
    // --- softmax + write ---
    {
      int r = q * 64 + lane;
      float m = (r < 400) ? pp[row][r] : -INFINITY;
      m = wave_rmax(m);
      if (lane == 0) wred[row][q] = m;
      __syncthreads();
      float gm = wred[row][0];
#pragma unroll
      for (int i = 1; i < 8; ++i) gm = fmaxf(gm, wred[row][i]);
      __syncthreads();
      float e = 0.f;
      if (r < 400) e = expf(pp[row][r] - gm);
      float sum = wave_rsum(e);
      if (lane == 0) wred[row][q] = sum;
      __syncthreads();
      float gs = 0.f;
#pragma unroll
      for (int i = 0; i < 8; ++i) gs += wred[row][i];
      float inv = 1.f / gs;
      if (r < 400) out_ratt[(size_t)(b0 + row) * 400 + r] = e * inv;
    }
  } else {
    // ---------------- scores role: one batch row ----------------
    int b = blockIdx.x - 256;
    if (t >= 200 && t < 400) x2hi[t - 200] = X2[(size_t)b * ADIMd + t];
    __syncthreads();
    const float4* xh = (const float4*)x2hi;
    for (int c = 0; c < 2; ++c) {
      int abase = w * 16 + c * 8;
      int ei[8];
#pragma unroll
      for (int u = 0; u < 8; ++u) ei[u] = e_space[(size_t)b * AA + abase + u];
      float p[8];
      if (lane < 50) {
        float4 xv = xh[lane];
#pragma unroll
        for (int u = 0; u < 8; ++u) {
          float4 vv = ((const float4*)(ent_emb + (size_t)ei[u] * ENTd))[lane];
          p[u] = dot4(vv, xv);
        }
      } else {
#pragma unroll
        for (int u = 0; u < 8; ++u) p[u] = 0.f;
      }
#pragma unroll
      for (int off = 32; off > 0; off >>= 1) {
#pragma unroll
        for (int u = 0; u < 8; ++u) p[u] += __shfl_xor(p[u], off);
      }
      if (lane == 0) {
#pragma unroll
        for (int u = 0; u < 8; ++u) scl[abase + u] = p[u];
      }
    }
    __syncthreads();
    float sc = -INFINITY;
    if (t < 256) {
      int r = r_space[(size_t)b * AA + t];
      sc = scl[t] + RX[(size_t)b * NRr + r] -
           (1.f - mask[(size_t)b * AA + t]) * 1e31f;
    }
    __syncthreads();
    if (w < 4) {
      float m = wave_rmax(sc);
      if (lane == 0) wr[w] = m;
    }
    __syncthreads();
    float gm = fmaxf(fmaxf(wr[0], wr[1]), fmaxf(wr[2], wr[3]));
    float e = (t < 256) ? expf(sc - gm) : 0.f;
    __syncthreads();
    if (w < 4) {
      float s2 = wave_rsum(e);
      if (lane == 0) wr[w] = s2;
    }
    __syncthreads();
    float gs = wr[0] + wr[1] + wr[2] + wr[3];
    float p = e / gs;
    if (t < 256) out_dist[(size_t)b * AA + t] = p;
    float ent = (t < 256) ? -p * logf(p + 1e-20f) : 0.f;
    __syncthreads();
    if (w < 4) {
      float s3 = wave_rsum(ent);
      if (lane == 0) wr[w] = s3;
    }
    __syncthreads();
    if (t == 0) out_ent[b] = wr[0] + wr[1] + wr[2] + wr[3];
  }
}

// ---------------------------------------------------------------------------
extern "C" void kernel_launch(void* const* d_in, const int* in_sizes, int n_in,
                              void* d_out, int out_size, void* d_ws,
                              size_t ws_size, hipStream_t stream) {
  const float* H = (const float*)d_in[0];
  const float* mask = (const float*)d_in[1];
  const float* ent_emb = (const float*)d_in[2];
  const float* rel_emb = (const float*)d_in[3];
  const float* W1 = (const float*)d_in[4];
  const float* b1 = (const float*)d_in[5];
  const float* W2 = (const float*)d_in[6];
  const float* b2 = (const float*)d_in[7];
  const float* W3 = (const float*)d_in[8];
  const float* b3 = (const float*)d_in[9];
  const float* W4 = (const float*)d_in[10];
  const float* b4 = (const float*)d_in[11];
  const float* W5 = (const float*)d_in[12];
  const float* b5 = (const float*)d_in[13];
  const float* W6 = (const float*)d_in[14];
  const float* b6 = (const float*)d_in[15];
  const float* Watt = (const float*)d_in[16];
  const float* batt = (const float*)d_in[17];
  const int* e_idx = (const int*)d_in[18];
  const int* q_idx = (const int*)d_in[19];
  const int* pred_id = (const int*)d_in[20];
  const int* r_space = (const int*)d_in[21];
  const int* e_space = (const int*)d_in[22];

  float* ws = (float*)d_ws;
  float* RK = ws;                   // 80000
  float* S_T = ws + 80000;          // 80000  [200][400]
  float* cvec = ws + 160000;        // 512
  float* P = ws + 160512;           // 40000
  float* Q_T = ws + 200512;         // 40000  [200][200]
  float* W6bb = ws + 240512;        // 40000
  float* REatt = ws + 280512;       // 80000  [400][200]
  float* relT = ws + 360512;        // 80000  [200][400]
  float* WaT = ws + 440512;         // 80000  [400][200]
  float* W1T = ws + 520512;         // 320000 [800][400]
  float* W2T = ws + 840512;         // 160000 [400][400]
  float* ab = ws + 1000512;         // 256
  float* v1 = ws + 1000768;         // 256
  float* X = ws + 1001024;          // 204800
  float* X2 = ws + 1205824;         // 204800
  float* RX = ws + 1410624;         // 204800 [512][400]

  float* out = (float*)d_out;
  float* out_dist = out;                 // [512,256]
  float* out_ent = out + BB * AA;        // [512]
  float* out_ratt = out + BB * AA + BB;  // [512,400]

  hipLaunchKernelGGL(prep1_kernel, dim3(297), dim3(256), 0, stream, rel_emb,
                     W4, b4, W5, b5, W6, Watt, W1, W2, RK, P, W6bb, ab, relT,
                     WaT, W1T, W2T);
  hipLaunchKernelGGL(prep2_x1_kernel, dim3(382), dim3(1024), 0, stream,
                     rel_emb, W3, b3, W6, Watt, batt, b6, RK, P, W6bb, ab,
                     S_T, cvec, Q_T, REatt, v1, ent_emb, H, e_idx, q_idx,
                     W1T, b1, X);
  hipLaunchKernelGGL(x2rx_kernel, dim3(256), dim3(1024), 0, stream, X, W2T,
                     b2, relT, X2, RX);
  hipLaunchKernelGGL(tail_kernel, dim3(768), dim3(1024), 0, stream, ent_emb,
                     pred_id, X2, S_T, cvec, Q_T, REatt, relT, WaT, v1, RX,
                     r_space, e_space, mask, out_ratt, out_dist, out_ent);
}

// Round 12
// 99.177 us; speedup vs baseline: 2.5509x; 1.0273x over previous
//
#include <hip/hip_runtime.h>
#include <cstdint>
#include <cstddef>

#define BB 512
#define NEn 100000
#define NRr 400
#define AA 256
#define ENTd 200
#define RELd 200
#define HISTd 400
#define ADIMd 400

__device__ __forceinline__ float dot4(const float4 a, const float4 b) {
  return a.x * b.x + a.y * b.y + a.z * b.z + a.w * b.w;
}
__device__ __forceinline__ void fma4(float4& a, const float4 w, const float c) {
  a.x += w.x * c; a.y += w.y * c; a.z += w.z * c; a.w += w.w * c;
}
__device__ __forceinline__ float wave_rmax(float v) {
#pragma unroll
  for (int off = 32; off > 0; off >>= 1) v = fmaxf(v, __shfl_xor(v, off));
  return v;
}
__device__ __forceinline__ float wave_rsum(float v) {
#pragma unroll
  for (int off = 32; off > 0; off >>= 1) v += __shfl_xor(v, off);
  return v;
}

// ---------------------------------------------------------------------------
// prep1: RK, P, W6bb, ab + tiled transposes relT/WaT/W1T/W2T  (unchanged)
// ---------------------------------------------------------------------------
__global__ __launch_bounds__(256) void prep1_kernel(
    const float* __restrict__ rel_emb, const float* __restrict__ W4,
    const float* __restrict__ b4, const float* __restrict__ W5,
    const float* __restrict__ b5, const float* __restrict__ W6,
    const float* __restrict__ Watt, const float* __restrict__ W1,
    const float* __restrict__ W2, float* __restrict__ RK,
    float* __restrict__ P, float* __restrict__ W6bb, float* __restrict__ ab,
    float* __restrict__ relT, float* __restrict__ WaT,
    float* __restrict__ W1T, float* __restrict__ W2T) {
  int t = threadIdx.x;
  int blk = blockIdx.x;
  if (blk == 0) {
    __shared__ float rs[RELd];
    if (t < RELd) {
      float s = 0.f;
      for (int r = 0; r < NRr; r += 4) {
        s += rel_emb[(size_t)r * RELd + t] + rel_emb[(size_t)(r + 1) * RELd + t] +
             rel_emb[(size_t)(r + 2) * RELd + t] + rel_emb[(size_t)(r + 3) * RELd + t];
      }
      rs[t] = s;
    }
    __syncthreads();
    if (t < RELd) {
      float acc = b5[t];
      const float4* w = (const float4*)(W5 + (size_t)t * 400);
      const float4* rv = (const float4*)rs;
      for (int k = 0; k < 50; ++k) acc += dot4(w[k], rv[k]);
      ab[t] = acc;
    }
  } else if (blk <= 50) {
    int r0 = (blk - 1) * 8;
    __shared__ float re[8][RELd];
    for (int i = t; i < 8 * RELd; i += 256)
      re[i / RELd][i % RELd] = rel_emb[(size_t)(r0 + i / RELd) * RELd + i % RELd];
    __syncthreads();
    if (t < RELd) {
      float bv = b4[t];
      float acc[8];
#pragma unroll
      for (int s = 0; s < 8; ++s) acc[s] = bv;
      const float4* w = (const float4*)(W4 + (size_t)t * RELd);
      for (int k = 0; k < 50; ++k) {
        float4 wv = w[k];
#pragma unroll
        for (int s = 0; s < 8; ++s) acc[s] += dot4(wv, ((const float4*)re[s])[k]);
      }
#pragma unroll
      for (int s = 0; s < 8; ++s) RK[(size_t)(r0 + s) * RELd + t] = acc[s];
    }
  } else if (blk <= 75) {
    int i0 = (blk - 51) * 8;
    __shared__ float w6s[8][200];
    for (int i = t; i < 8 * 200; i += 256)
      w6s[i / 200][i % 200] = W6[(size_t)(i0 + i / 200) * 400 + i % 200];
    __syncthreads();
    if (t < 200) {
      int k = t;
      float acc[8] = {0, 0, 0, 0, 0, 0, 0, 0};
      for (int j = 0; j < 200; j += 4) {
        float r0v = W5[(size_t)j * 400 + 200 + k];
        float r1v = W5[(size_t)(j + 1) * 400 + 200 + k];
        float r2v = W5[(size_t)(j + 2) * 400 + 200 + k];
        float r3v = W5[(size_t)(j + 3) * 400 + 200 + k];
#pragma unroll
        for (int s = 0; s < 8; ++s)
          acc[s] += w6s[s][j] * r0v + w6s[s][j + 1] * r1v + w6s[s][j + 2] * r2v +
                    w6s[s][j + 3] * r3v;
      }
#pragma unroll
      for (int s = 0; s < 8; ++s) P[(size_t)(i0 + s) * 200 + k] = 400.f * acc[s];
    }
  } else if (blk <= 100) {
    int u0 = (blk - 76) * 8;
    __shared__ float wbs[8][200];
    for (int i = t; i < 8 * 200; i += 256)
      wbs[i / 200][i % 200] = Watt[(size_t)(u0 + i / 200) * 600 + 400 + i % 200];
    __syncthreads();
    if (t < 200) {
      int j = t;
      float acc[8] = {0, 0, 0, 0, 0, 0, 0, 0};
      for (int i = 0; i < 200; i += 4) {
        float r0v = W6[(size_t)i * 400 + 200 + j];
        float r1v = W6[(size_t)(i + 1) * 400 + 200 + j];
        float r2v = W6[(size_t)(i + 2) * 400 + 200 + j];
        float r3v = W6[(size_t)(i + 3) * 400 + 200 + j];
#pragma unroll
        for (int s = 0; s < 8; ++s)
          acc[s] += wbs[s][i] * r0v + wbs[s][i + 1] * r1v + wbs[s][i + 2] * r2v +
                    wbs[s][i + 3] * r3v;
      }
#pragma unroll
      for (int s = 0; s < 8; ++s) W6bb[(size_t)(u0 + s) * 200 + j] = acc[s];
    }
  } else {
    __shared__ float tlds[64][65];
    int tb = blk - 101;
    const float* src;
    float* dst;
    int M, N, LD, ti, tj;
    if (tb < 28) {
      src = rel_emb; dst = relT; M = 400; N = 200; LD = 200;
      ti = tb / 4; tj = tb % 4;
    } else if (tb < 56) {
      tb -= 28;
      src = Watt; dst = WaT; M = 200; N = 400; LD = 600;
      ti = tb / 7; tj = tb % 7;
    } else if (tb < 147) {
      tb -= 56;
      src = W1; dst = W1T; M = 400; N = 800; LD = 800;
      ti = tb / 13; tj = tb % 13;
    } else {
      tb -= 147;
      src = W2; dst = W2T; M = 400; N = 400; LD = 400;
      ti = tb / 7; tj = tb % 7;
    }
    int i0 = ti * 64, j0 = tj * 64;
    for (int idx = t; idx < 4096; idx += 256) {
      int r = idx >> 6, c = idx & 63;
      int i = i0 + r, j = j0 + c;
      if (i < M && j < N) tlds[r][c] = src[(size_t)i * LD + j];
    }
    __syncthreads();
    for (int idx = t; idx < 4096; idx += 256) {
      int r = idx >> 6, c = idx & 63;
      int j = j0 + r, i = i0 + c;
      if (i < M && j < N) dst[(size_t)j * M + i] = tlds[c][r];
    }
  }
}

// ---------------------------------------------------------------------------
// prep2_x1: blocks 0..125 = prep2 roles; blocks 126..253 = x1 (4 rows, f4)
// ---------------------------------------------------------------------------
__global__ __launch_bounds__(1024) void prep2_x1_kernel(
    const float* __restrict__ rel_emb, const float* __restrict__ W3,
    const float* __restrict__ b3, const float* __restrict__ W6,
    const float* __restrict__ Watt, const float* __restrict__ batt,
    const float* __restrict__ b6, const float* __restrict__ RK,
    const float* __restrict__ P, const float* __restrict__ W6bb,
    const float* __restrict__ ab, float* __restrict__ S_T,
    float* __restrict__ cvec, float* __restrict__ Q_T,
    float* __restrict__ REatt, float* __restrict__ v1,
    const float* __restrict__ ent_emb, const float* __restrict__ H,
    const int* __restrict__ e_idx, const int* __restrict__ q_idx,
    const float* __restrict__ W1T, const float* __restrict__ b1,
    float* __restrict__ X) {
  int t = threadIdx.x;
  int blk = blockIdx.x;
  if (blk < 50) {
    int r0 = blk * 8;
    __shared__ float rks[8][200];
    __shared__ float b3s[200];
    for (int i = t; i < 1600; i += 1024)
      rks[i / 200][i % 200] = RK[(size_t)r0 * 200 + i];
    if (t < 200) b3s[t] = b3[t];
    __syncthreads();
    if (t < 200) {
      int i = t;
      float acc[8] = {0, 0, 0, 0, 0, 0, 0, 0};
      for (int j = 0; j < 200; j += 4) {
        float w0 = W3[(size_t)j * 200 + i];
        float w1 = W3[(size_t)(j + 1) * 200 + i];
        float w2 = W3[(size_t)(j + 2) * 200 + i];
        float w3v = W3[(size_t)(j + 3) * 200 + i];
#pragma unroll
        for (int s = 0; s < 8; ++s)
          acc[s] += w0 * rks[s][j] + w1 * rks[s][j + 1] + w2 * rks[s][j + 2] +
                    w3v * rks[s][j + 3];
      }
      float4 s0 = make_float4(acc[0], acc[1], acc[2], acc[3]);
      float4 s1 = make_float4(acc[4], acc[5], acc[6], acc[7]);
      *(float4*)(S_T + (size_t)i * 400 + r0) = s0;
      *(float4*)(S_T + (size_t)i * 400 + r0 + 4) = s1;
    }
    if (t < 256) {
      int w = t >> 6, lane = t & 63;
      float p0 = 0.f, p1 = 0.f;
      for (int j = lane; j < 200; j += 64) {
        p0 += b3s[j] * rks[w][j];
        p1 += b3s[j] * rks[w + 4][j];
      }
      p0 = wave_rsum(p0);
      p1 = wave_rsum(p1);
      if (lane == 0) {
        cvec[r0 + w] = p0;
        cvec[r0 + w + 4] = p1;
      }
    }
  } else if (blk < 75) {
    int u0 = (blk - 50) * 8;
    __shared__ float wbs[8][200];
    for (int i = t; i < 1600; i += 1024)
      wbs[i / 200][i % 200] = Watt[(size_t)(u0 + i / 200) * 600 + 400 + i % 200];
    __syncthreads();
    if (t < 200) {
      int k = t;
      float acc[8] = {0, 0, 0, 0, 0, 0, 0, 0};
      for (int i = 0; i < 200; i += 4) {
        float r0v = P[(size_t)i * 200 + k];
        float r1v = P[(size_t)(i + 1) * 200 + k];
        float r2v = P[(size_t)(i + 2) * 200 + k];
        float r3v = P[(size_t)(i + 3) * 200 + k];
#pragma unroll
        for (int s = 0; s < 8; ++s)
          acc[s] += wbs[s][i] * r0v + wbs[s][i + 1] * r1v + wbs[s][i + 2] * r2v +
                    wbs[s][i + 3] * r3v;
      }
      float4 s0 = make_float4(acc[0], acc[1], acc[2], acc[3]);
      float4 s1 = make_float4(acc[4], acc[5], acc[6], acc[7]);
      *(float4*)(Q_T + (size_t)k * 200 + u0) = s0;
      *(float4*)(Q_T + (size_t)k * 200 + u0 + 4) = s1;
    }
  } else if (blk < 125) {
    int r0 = (blk - 75) * 8;
    __shared__ float rels[8][200];
    for (int i = t; i < 1600; i += 1024)
      rels[i / 200][i % 200] = rel_emb[(size_t)r0 * 200 + i];
    __syncthreads();
    if (t < 200) {
      float acc[8] = {0, 0, 0, 0, 0, 0, 0, 0};
      const float4* w = (const float4*)(W6bb + (size_t)t * 200);
      for (int k = 0; k < 50; ++k) {
        float4 wv = w[k];
#pragma unroll
        for (int s = 0; s < 8; ++s) acc[s] += dot4(wv, ((const float4*)rels[s])[k]);
      }
#pragma unroll
      for (int s = 0; s < 8; ++s) REatt[(size_t)(r0 + s) * 200 + t] = acc[s];
    }
  } else if (blk == 125) {
    __shared__ float abs_[200];
    __shared__ float us[200];
    if (t < 200) abs_[t] = ab[t];
    __syncthreads();
    if (t < 200) {
      float u = b6[t];
      const float4* w = (const float4*)(W6 + (size_t)t * 400);
      const float4* rv = (const float4*)abs_;
      for (int k = 0; k < 50; ++k) u += dot4(w[k], rv[k]);
      us[t] = u;
    }
    __syncthreads();
    if (t < 200) {
      float v = batt[t];
      const float4* w = (const float4*)(Watt + (size_t)t * 600 + 400);
      const float4* rv = (const float4*)us;
      for (int k = 0; k < 50; ++k) v += dot4(w[k], rv[k]);
      v1[t] = v;
    }
  } else {
    // ----- x1 role (f4, R=4): rows b0..b0+3; thread owns 4 j's, 8-way k ---
    int b0 = (blk - 126) * 4;
    __shared__ float cv[4][800];   // 12.8 KB
    __shared__ float prt[12800];   // 51.2 KB  [(h*4+s)*400 + j]
    for (int i = t; i < 3200; i += 1024) {
      int s = i / 800, k = i % 800;
      float v;
      if (k < ENTd)
        v = ent_emb[(size_t)e_idx[b0 + s] * ENTd + k];
      else if (k < ENTd + HISTd)
        v = H[(size_t)(b0 + s) * HISTd + (k - ENTd)];
      else
        v = rel_emb[(size_t)q_idx[b0 + s] * RELd + (k - ENTd - HISTd)];
      cv[s][k] = v;
    }
    __syncthreads();
    if (t < 800) {
      int g = t % 100, h = t / 100;  // h in [0,8), k-chunk 100
      float4 acc[4];
#pragma unroll
      for (int s = 0; s < 4; ++s) acc[s] = make_float4(0, 0, 0, 0);
      const float4* wp = ((const float4*)W1T) + g;
      int k0 = h * 100;
#pragma unroll 4
      for (int kk = 0; kk < 100; ++kk) {
        int k = k0 + kk;
        float4 wv = wp[(size_t)k * 100];
#pragma unroll
        for (int s = 0; s < 4; ++s) fma4(acc[s], wv, cv[s][k]);
      }
#pragma unroll
      for (int s = 0; s < 4; ++s)
        ((float4*)prt)[(h * 4 + s) * 100 + g] = acc[s];
    }
    __syncthreads();
    for (int i = t; i < 1600; i += 1024) {
      int s = i / 400, j = i % 400;
      float a = b1[j];
#pragma unroll
      for (int h = 0; h < 8; ++h) a += prt[(h * 4 + s) * 400 + j];
      X[(size_t)(b0 + s) * ADIMd + j] = fmaxf(a, 0.f);
    }
  }
}

// ---------------------------------------------------------------------------
// x2rx (f4): X2 = W2T^T.X + b2 ; RX = relT^T-dot. 1024 thr, R=2, grid 256
// ---------------------------------------------------------------------------
__global__ __launch_bounds__(1024) void x2rx_kernel(
    const float* __restrict__ X, const float* __restrict__ W2T,
    const float* __restrict__ b2, const float* __restrict__ relT,
    float* __restrict__ X2, float* __restrict__ RX) {
  int b0 = blockIdx.x * 2;
  int t = threadIdx.x;
  __shared__ float cv[2][400];
  __shared__ float prt[6400];
  __shared__ float x2lo[2][200];
  for (int i = t; i < 800; i += 1024) cv[i / 400][i % 400] = X[(size_t)b0 * 400 + i];
  __syncthreads();
  if (t < 800) {
    int g = t % 100, h = t / 100;  // h in [0,8), k-chunk 50
    float4 accA = make_float4(0, 0, 0, 0);
    float4 accB = make_float4(0, 0, 0, 0);
    const float4* wp = ((const float4*)W2T) + g;
    int k0 = h * 50;
#pragma unroll 4
    for (int kk = 0; kk < 50; ++kk) {
      int k = k0 + kk;
      float4 wv = wp[(size_t)k * 100];
      fma4(accA, wv, cv[0][k]);
      fma4(accB, wv, cv[1][k]);
    }
    ((float4*)prt)[(h * 2 + 0) * 100 + g] = accA;
    ((float4*)prt)[(h * 2 + 1) * 100 + g] = accB;
  }
  __syncthreads();
  if (t < 800) {
    int s = t / 400, j = t % 400;
    float a = b2[j];
#pragma unroll
    for (int h = 0; h < 8; ++h) a += prt[(h * 2 + s) * 400 + j];
    X2[(size_t)(b0 + s) * ADIMd + j] = a;
    if (j < 200) x2lo[s][j] = a;
  }
  __syncthreads();
  if (t < 800) {
    int g = t % 100, h = t / 100;  // h in [0,8), k-chunk 25
    float4 accA = make_float4(0, 0, 0, 0);
    float4 accB = make_float4(0, 0, 0, 0);
    const float4* rp = ((const float4*)relT) + g;
    int k0 = h * 25;
#pragma unroll 4
    for (int kk = 0; kk < 25; ++kk) {
      int k = k0 + kk;
      float4 wv = rp[(size_t)k * 100];
      fma4(accA, wv, x2lo[0][k]);
      fma4(accB, wv, x2lo[1][k]);
    }
    ((float4*)prt)[(h * 2 + 0) * 100 + g] = accA;
    ((float4*)prt)[(h * 2 + 1) * 100 + g] = accB;
  }
  __syncthreads();
  if (t < 800) {
    int s = t / 400, r = t % 400;
    float a = 0.f;
#pragma unroll
    for (int h = 0; h < 8; ++h) a += prt[(h * 2 + s) * 400 + r];
    RX[(size_t)(b0 + s) * NRr + r] = a;
  }
}

// ---------------------------------------------------------------------------
// tail: blocks 0..127 = fused_mid (R=4, f4 phases); 128..639 = scores.
// ---------------------------------------------------------------------------
__global__ __launch_bounds__(1024) void tail_kernel(
    const float* __restrict__ ent_emb, const int* __restrict__ pred_id,
    const float* __restrict__ X2, const float* __restrict__ S_T,
    const float* __restrict__ cvec, const float* __restrict__ Q_T,
    const float* __restrict__ REatt, const float* __restrict__ relT,
    const float* __restrict__ WaT, const float* __restrict__ v1c,
    const float* __restrict__ RX, const int* __restrict__ r_space,
    const int* __restrict__ e_space, const float* __restrict__ mask,
    float* __restrict__ out_ratt, float* __restrict__ out_dist,
    float* __restrict__ out_ent) {
  int t = threadIdx.x;
  int w = t >> 6, lane = t & 63;
  // fused role shared
  __shared__ float pes[4][200];
  __shared__ float x2s[4][400];
  __shared__ float pp[4][400];
  __shared__ float av[4][200];
  __shared__ float prt[12800];
  __shared__ float wred[4][4];
  // scores role shared
  __shared__ float x2hi[200];
  __shared__ float scl[256];
  __shared__ float wr[4];

  if (blockIdx.x < 128) {
    int b0 = blockIdx.x * 4;
    // pes (800) + x2s (1600) = 2400 elements, strided
    for (int i = t; i < 2400; i += 1024) {
      if (i < 800)
        pes[i / 200][i % 200] =
            ent_emb[(size_t)pred_id[b0 + i / 200] * ENTd + i % 200];
      else {
        int k = i - 800;
        x2s[k / 400][k % 400] = X2[(size_t)b0 * 400 + k];
      }
    }
    __syncthreads();
    // --- la (f4, R=4): thread owns 4 r's, 8-way k-split (chunk 25) ---
    if (t < 800) {
      int g = t % 100, h = t / 100;
      float4 acc[4];
#pragma unroll
      for (int s = 0; s < 4; ++s) acc[s] = make_float4(0, 0, 0, 0);
      const float4* sp = ((const float4*)S_T) + g;
      int k0 = h * 25;
#pragma unroll 5
      for (int kk = 0; kk < 25; ++kk) {
        int k = k0 + kk;
        float4 wv = sp[(size_t)k * 100];
#pragma unroll
        for (int s = 0; s < 4; ++s) fma4(acc[s], wv, pes[s][k]);
      }
#pragma unroll
      for (int s = 0; s < 4; ++s)
        ((float4*)prt)[(h * 4 + s) * 100 + g] = acc[s];
    }
    __syncthreads();
    for (int i = t; i < 1600; i += 1024) {
      int s = i / 400, r = i % 400;
      float a = cvec[r];
#pragma unroll
      for (int h = 0; h < 8; ++h) a += prt[(h * 4 + s) * 400 + r];
      pp[s][r] = a;
    }
    __syncthreads();
    int row = w >> 2, q = w & 3;  // 4 waves per batch row
    // --- softmax(pp rows) ---
    {
      float m = -INFINITY;
      for (int r = q * 64 + lane; r < 400; r += 256) m = fmaxf(m, pp[row][r]);
      m = wave_rmax(m);
      if (lane == 0) wred[row][q] = m;
      __syncthreads();
      float gm = fmaxf(fmaxf(wred[row][0], wred[row][1]),
                       fmaxf(wred[row][2], wred[row][3]));
      __syncthreads();
      float sum = 0.f;
      for (int r = q * 64 + lane; r < 400; r += 256) {
        float e = expf(pp[row][r] - gm);
        pp[row][r] = e;
        sum += e;
      }
      sum = wave_rsum(sum);
      if (lane == 0) wred[row][q] = sum;
      __syncthreads();
      float inv =
          1.f / (wred[row][0] + wred[row][1] + wred[row][2] + wred[row][3]);
      for (int r = q * 64 + lane; r < 400; r += 256) pp[row][r] *= inv;
    }
    __syncthreads();
    // --- attv (f4, R=4): thread owns 4 j's, 16-way split (chunk 25) ---
    if (t < 800) {
      int g = t % 50, h = t / 50;  // h in [0,16)
      float4 acc[4];
      if (h == 0) {
        float4 v = ((const float4*)v1c)[g];
#pragma unroll
        for (int s = 0; s < 4; ++s) acc[s] = v;
      } else {
#pragma unroll
        for (int s = 0; s < 4; ++s) acc[s] = make_float4(0, 0, 0, 0);
      }
      {  // WaT [400][200], k-chunk 25
        const float4* wp = ((const float4*)WaT) + g;
        int k0 = h * 25;
#pragma unroll 5
        for (int kk = 0; kk < 25; ++kk) {
          int k = k0 + kk;
          float4 wv = wp[(size_t)k * 50];
#pragma unroll
          for (int s = 0; s < 4; ++s) fma4(acc[s], wv, x2s[s][k]);
        }
      }
      if (h < 8) {  // Q_T [200][200], k-chunk 25
        const float4* qp = ((const float4*)Q_T) + g;
        int k0 = h * 25;
#pragma unroll 5
        for (int kk = 0; kk < 25; ++kk) {
          int k = k0 + kk;
          float4 wv = qp[(size_t)k * 50];
#pragma unroll
          for (int s = 0; s < 4; ++s) fma4(acc[s], wv, pes[s][k]);
        }
      }
      {  // REatt [400][200], r-chunk 25
        const float4* rp = ((const float4*)REatt) + g;
        int r0 = h * 25;
#pragma unroll 5
        for (int kk = 0; kk < 25; ++kk) {
          int r = r0 + kk;
          float4 wv = rp[(size_t)r * 50];
#pragma unroll
          for (int s = 0; s < 4; ++s) fma4(acc[s], wv, pp[s][r]);
        }
      }
#pragma unroll
      for (int s = 0; s < 4; ++s)
        ((float4*)prt)[(h * 4 + s) * 50 + g] = acc[s];
    }
    __syncthreads();
    if (t < 800) {
      int s = t / 200, j = t % 200;
      float a = 0.f;
#pragma unroll
      for (int h = 0; h < 16; ++h) a += prt[(h * 4 + s) * 200 + j];
      av[s][j] = a;
    }
    __syncthreads();
    // --- logits (f4): relT [200][400], thread owns 4 r's, 8-way (chunk 25) ---
    if (t < 800) {
      int g = t % 100, h = t / 100;
      float4 acc[4];
#pragma unroll
      for (int s = 0; s < 4; ++s) acc[s] = make_float4(0, 0, 0, 0);
      const float4* rp = ((const float4*)relT) + g;
      int k0 = h * 25;
#pragma unroll 5
      for (int kk = 0; kk < 25; ++kk) {
        int k = k0 + kk;
        float4 wv = rp[(size_t)k * 100];
#pragma unroll
        for (int s = 0; s < 4; ++s) fma4(acc[s], wv, av[s][k]);
      }
#pragma unroll
      for (int s = 0; s < 4; ++s)
        ((float4*)prt)[(h * 4 + s) * 100 + g] = acc[s];
    }
    __syncthreads();
    for (int i = t; i < 1600; i += 1024) {
      int s = i / 400, r = i % 400;
      float a = 0.f;
#pragma unroll
      for (int h = 0; h < 8; ++h) a += prt[(h * 4 + s) * 400 + r];
      pp[s][r] = a;
    }
    __syncthreads();
    // --- softmax + write ---
    {
      float m = -INFINITY;
      for (int r = q * 64 + lane; r < 400; r += 256) m = fmaxf(m, pp[row][r]);
      m = wave_rmax(m);
      if (lane == 0) wred[row][q] = m;
      __syncthreads();
      float gm = fmaxf(fmaxf(wred[row][0], wred[row][1]),
                       fmaxf(wred[row][2], wred[row][3]));
      __syncthreads();
      float sum = 0.f;
      for (int r = q * 64 + lane; r < 400; r += 256) {
        float e = expf(pp[row][r] - gm);
        pp[row][r] = e;
        sum += e;
      }
      sum = wave_rsum(sum);
      if (lane == 0) wred[row][q] = sum;
      __syncthreads();
      float inv =
          1.f / (wred[row][0] + wred[row][1] + wred[row][2] + wred[row][3]);
      for (int r = q * 64 + lane; r < 400; r += 256)
        out_ratt[(size_t)(b0 + row) * 400 + r] = pp[row][r] * inv;
    }
  } else {
    // ---------------- scores role: one batch row, 16 gathers in flight ----
    int b = blockIdx.x - 128;
    if (t >= 200 && t < 400) x2hi[t - 200] = X2[(size_t)b * ADIMd + t];
    __syncthreads();
    const float4* xh = (const float4*)x2hi;
    {
      int abase = w * 16;
      int ei[16];
#pragma unroll
      for (int u = 0; u < 16; ++u) ei[u] = e_space[(size_t)b * AA + abase + u];
      float p[16];
      if (lane < 50) {
        float4 xv = xh[lane];
#pragma unroll
        for (int u = 0; u < 16; ++u) {
          float4 vv = ((const float4*)(ent_emb + (size_t)ei[u] * ENTd))[lane];
          p[u] = dot4(vv, xv);
        }
      } else {
#pragma unroll
        for (int u = 0; u < 16; ++u) p[u] = 0.f;
      }
#pragma unroll
      for (int off = 32; off > 0; off >>= 1) {
#pragma unroll
        for (int u = 0; u < 16; ++u) p[u] += __shfl_xor(p[u], off);
      }
      if (lane == 0) {
#pragma unroll
        for (int u = 0; u < 16; ++u) scl[abase + u] = p[u];
      }
    }
    __syncthreads();
    float sc = -INFINITY;
    if (t < 256) {
      int r = r_space[(size_t)b * AA + t];
      sc = scl[t] + RX[(size_t)b * NRr + r] -
           (1.f - mask[(size_t)b * AA + t]) * 1e31f;
    }
    __syncthreads();
    if (w < 4) {
      float m = wave_rmax(sc);
      if (lane == 0) wr[w] = m;
    }
    __syncthreads();
    float gm = fmaxf(fmaxf(wr[0], wr[1]), fmaxf(wr[2], wr[3]));
    float e = (t < 256) ? expf(sc - gm) : 0.f;
    __syncthreads();
    if (w < 4) {
      float s2 = wave_rsum(e);
      if (lane == 0) wr[w] = s2;
    }
    __syncthreads();
    float gs = wr[0] + wr[1] + wr[2] + wr[3];
    float p = e / gs;
    if (t < 256) out_dist[(size_t)b * AA + t] = p;
    float ent = (t < 256) ? -p * logf(p + 1e-20f) : 0.f;
    __syncthreads();
    if (w < 4) {
      float s3 = wave_rsum(ent);
      if (lane == 0) wr[w] = s3;
    }
    __syncthreads();
    if (t == 0) out_ent[b] = wr[0] + wr[1] + wr[2] + wr[3];
  }
}

// ---------------------------------------------------------------------------
extern "C" void kernel_launch(void* const* d_in, const int* in_sizes, int n_in,
                              void* d_out, int out_size, void* d_ws,
                              size_t ws_size, hipStream_t stream) {
  const float* H = (const float*)d_in[0];
  const float* mask = (const float*)d_in[1];
  const float* ent_emb = (const float*)d_in[2];
  const float* rel_emb = (const float*)d_in[3];
  const float* W1 = (const float*)d_in[4];
  const float* b1 = (const float*)d_in[5];
  const float* W2 = (const float*)d_in[6];
  const float* b2 = (const float*)d_in[7];
  const float* W3 = (const float*)d_in[8];
  const float* b3 = (const float*)d_in[9];
  const float* W4 = (const float*)d_in[10];
  const float* b4 = (const float*)d_in[11];
  const float* W5 = (const float*)d_in[12];
  const float* b5 = (const float*)d_in[13];
  const float* W6 = (const float*)d_in[14];
  const float* b6 = (const float*)d_in[15];
  const float* Watt = (const float*)d_in[16];
  const float* batt = (const float*)d_in[17];
  const int* e_idx = (const int*)d_in[18];
  const int* q_idx = (const int*)d_in[19];
  const int* pred_id = (const int*)d_in[20];
  const int* r_space = (const int*)d_in[21];
  const int* e_space = (const int*)d_in[22];

  float* ws = (float*)d_ws;
  float* RK = ws;                   // 80000
  float* S_T = ws + 80000;          // 80000  [200][400]
  float* cvec = ws + 160000;        // 512
  float* P = ws + 160512;           // 40000
  float* Q_T = ws + 200512;         // 40000  [200][200]
  float* W6bb = ws + 240512;        // 40000
  float* REatt = ws + 280512;       // 80000  [400][200]
  float* relT = ws + 360512;        // 80000  [200][400]
  float* WaT = ws + 440512;         // 80000  [400][200]
  float* W1T = ws + 520512;         // 320000 [800][400]
  float* W2T = ws + 840512;         // 160000 [400][400]
  float* ab = ws + 1000512;         // 256
  float* v1 = ws + 1000768;         // 256
  float* X = ws + 1001024;          // 204800
  float* X2 = ws + 1205824;         // 204800
  float* RX = ws + 1410624;         // 204800 [512][400]

  float* out = (float*)d_out;
  float* out_dist = out;                 // [512,256]
  float* out_ent = out + BB * AA;        // [512]
  float* out_ratt = out + BB * AA + BB;  // [512,400]

  hipLaunchKernelGGL(prep1_kernel, dim3(297), dim3(256), 0, stream, rel_emb,
                     W4, b4, W5, b5, W6, Watt, W1, W2, RK, P, W6bb, ab, relT,
                     WaT, W1T, W2T);
  hipLaunchKernelGGL(prep2_x1_kernel, dim3(254), dim3(1024), 0, stream,
                     rel_emb, W3, b3, W6, Watt, batt, b6, RK, P, W6bb, ab,
                     S_T, cvec, Q_T, REatt, v1, ent_emb, H, e_idx, q_idx,
                     W1T, b1, X);
  hipLaunchKernelGGL(x2rx_kernel, dim3(256), dim3(1024), 0, stream, X, W2T,
                     b2, relT, X2, RX);
  hipLaunchKernelGGL(tail_kernel, dim3(640), dim3(1024), 0, stream, ent_emb,
                     pred_id, X2, S_T, cvec, Q_T, REatt, relT, WaT, v1, RX,
                     r_space, e_space, mask, out_ratt, out_dist, out_ent);
}